// Round 13
// baseline (2960.880 us; speedup 1.0000x reference)
//
#include <hip/hip_runtime.h>
#include <math.h>

#define B_TOT 16384
#define CELLS 36
#define YDIM 252       // 7*6*6
#define FEATP 448      // 416 padded to 448
#define FEAT_REAL 416
#define HDIM 2048
#define EMB_DIM 128
#define KSTEPS 50
#define NPART 8        // e_part slabs = HDIM/256

typedef unsigned short ushort_t;
typedef __attribute__((ext_vector_type(8))) short short8v;
typedef __attribute__((ext_vector_type(4))) float float4v;

__device__ __forceinline__ float clip01(float x){ return fminf(fmaxf(x, 0.f), 1.f); }
__device__ __forceinline__ float tanh_fast(float u){
  float e = __expf(2.f * u);
  return 1.f - 2.f / (e + 1.f);
}
__device__ __forceinline__ float gelu_f(float x){
  float u = 0.7978845608028654f * (x + 0.044715f * x * x * x);
  return 0.5f * x * (1.f + tanh_fast(u));
}
__device__ __forceinline__ float dgelu_f(float x){
  float x2 = x * x;
  float u = 0.7978845608028654f * (x + 0.044715f * x2 * x);
  float t = tanh_fast(u);
  return 0.5f * (1.f + t) + 0.5f * x * (1.f - t * t) * 0.7978845608028654f * (1.f + 0.134145f * x2);
}
__device__ __forceinline__ float clipmask(float y){ return (y == 0.f || y == 1.f) ? 0.5f : 1.f; }
__device__ __forceinline__ ushort_t f2bf(float x){
  union { float f; unsigned u; } v; v.f = x;
  unsigned r = v.u + 0x7fffu + ((v.u >> 16) & 1u);
  return (ushort_t)(r >> 16);
}
__device__ __forceinline__ float bf2f(ushort_t h){
  union { unsigned u; float f; } v; v.u = ((unsigned)h) << 16; return v.f;
}
__device__ __forceinline__ void load_lds16(const void* g, void* l){
  __builtin_amdgcn_global_load_lds((const __attribute__((address_space(1))) unsigned int*)g,
                                   (__attribute__((address_space(3))) unsigned int*)l, 16, 0, 0);
}
__device__ __forceinline__ void store16(ushort_t* dst, const float* x){
  short8v r0, r1;
#pragma unroll
  for (int i = 0; i < 8; ++i){ r0[i] = (short)f2bf(x[i]); r1[i] = (short)f2bf(x[8 + i]); }
  *(short8v*)dst = r0;
  *(short8v*)&dst[8] = r1;
}
// m204 bijective XCD swizzle
__device__ __forceinline__ void xcd_swizzle(int GX, int GY, int& bx, int& by){
  int nwg = GX * GY;
  int orig = by * GX + bx;
  int q = nwg >> 3, r = nwg & 7;
  int xcd = orig & 7, loc = orig >> 3;
  int lin = (xcd < r ? xcd * (q + 1) : r * (q + 1) + (xcd - r) * q) + loc;
  bx = lin % GX; by = lin / GX;
}

// ---------------- small kernels ----------------
__global__ void k_zero_acc(double* acc){ acc[0] = 0.0; acc[1] = 0.0; acc[2] = 0.0; }

__global__ void k_sigma(const int* __restrict__ k_idx, float* __restrict__ sigma_b){
  int b = blockIdx.x * blockDim.x + threadIdx.x;
  if (b >= B_TOT) return;
  int i = (KSTEPS - 1) - k_idx[b];
  float t = (float)i / (float)(KSTEPS - 1);
  float ang = (1.f - t) * 1.57079632679489662f;
  float c = cosf(ang);
  sigma_b[b] = 0.01f + 0.94f * c * c;
}

__global__ void k_cast(const float* __restrict__ in, ushort_t* __restrict__ out, int n){
  int gid = blockIdx.x * blockDim.x + threadIdx.x;
  if (gid < n) out[gid] = f2bf(in[gid]);
}
// W1T[h][f] (f padded to 448)
__global__ void k_w1t(const float* __restrict__ W1, ushort_t* __restrict__ W1T){
  int gid = blockIdx.x * blockDim.x + threadIdx.x;
  if (gid >= HDIM * FEATP) return;
  int h = gid / FEATP, f = gid - h * FEATP;
  W1T[gid] = (f < FEAT_REAL) ? f2bf(W1[(size_t)f * HDIM + h]) : (ushort_t)0;
}
// merged: W2bf = cast(W2) (row-major), W2T[n][k] = W2[k][n] — one read of W2
__global__ __launch_bounds__(256) void k_w2x(const float* __restrict__ W2,
                                             ushort_t* __restrict__ W2bf,
                                             ushort_t* __restrict__ W2T){
  __shared__ float tile[32][33];
  int x0 = blockIdx.x << 5, y0 = blockIdx.y << 5;
  int tx = threadIdx.x & 31, ty = threadIdx.x >> 5;
#pragma unroll
  for (int i = 0; i < 4; ++i){
    float v = W2[(size_t)(y0 + ty + i * 8) * HDIM + (x0 + tx)];
    tile[ty + i * 8][tx] = v;
    W2bf[(size_t)(y0 + ty + i * 8) * HDIM + (x0 + tx)] = f2bf(v);
  }
  __syncthreads();
#pragma unroll
  for (int i = 0; i < 4; ++i)
    W2T[(size_t)(x0 + ty + i * 8) * HDIM + (y0 + tx)] = f2bf(tile[tx][ty + i * 8]);
}

// static cols of feat: 252..447 (cond, emb, zero pad)
__global__ void k_feat_static(const float* __restrict__ cond, const float* __restrict__ k_emb,
                              const int* __restrict__ k_idx, ushort_t* __restrict__ feat, int Mc){
  int gid = blockIdx.x * blockDim.x + threadIdx.x;
  if (gid >= Mc * 196) return;
  int i = gid / 196, c = gid - i * 196;
  float v;
  if (c < CELLS)            v = cond[(size_t)i * CELLS + c];
  else if (c < CELLS + EMB_DIM) v = k_emb[(size_t)k_idx[i] * EMB_DIM + (c - CELLS)];
  else                      v = 0.f;
  feat[(size_t)i * FEATP + YDIM + c] = f2bf(v);
}

// noise + direct feat write
__global__ void k_noise(const float* __restrict__ y, const float* __restrict__ eps,
                        const float* __restrict__ sigma_b, float* __restrict__ out,
                        ushort_t* __restrict__ feat, int Mc){
  int gid = blockIdx.x * blockDim.x + threadIdx.x;
  if (gid >= Mc * CELLS) return;
  int i = gid / CELLS, cell = gid - i * CELLS;
  float sigma = sigma_b[i];
  float sq = sqrtf(fmaxf(1.f - sigma * sigma, 1e-8f));
  const float* yp = y + (size_t)i * YDIM + cell;
  const float* ep = eps + (size_t)i * YDIM + cell;
  float yh[7];
#pragma unroll
  for (int ch = 0; ch < 7; ++ch){
    float e = ep[ch * CELLS] * 0.1f;
    yh[ch] = clip01(sq * yp[ch * CELLS] + sigma * e);
  }
  bool filled = yh[0] > 0.5f;
  float s = 0.f;
#pragma unroll
  for (int ch = 1; ch < 7; ++ch) s += yh[ch];
  float* op = out + (size_t)i * YDIM + cell;
  ushort_t* fp = feat + (size_t)i * FEATP + cell;
  op[0] = yh[0];
  fp[0] = f2bf(yh[0]);
#pragma unroll
  for (int ch = 1; ch < 7; ++ch){
    float v = yh[ch];
    if (filled) v = v / (s + 1e-8f);
    v = clip01(v);
    op[ch * CELLS] = v;
    fp[ch * CELLS] = f2bf(v);
  }
}

// y_neg init + feat write
__global__ void k_makeneg(const float* __restrict__ y_true, const float* __restrict__ sel,
                          const float* __restrict__ rv, float* __restrict__ y_neg,
                          ushort_t* __restrict__ feat, int b0, int Mc){
  int w = (blockIdx.x * blockDim.x + threadIdx.x) >> 6;
  int lane = threadIdx.x & 63;
  if (w >= Mc) return;
  int b = b0 + w;
  int c = lane;
  bool active = c < CELLS;
  float yt0 = active ? y_true[(size_t)b * YDIM + c] : 0.f;
  bool filled = active && (yt0 > 0.5f);
  unsigned long long bal = __ballot(filled);
  int n_filled = __popcll(bal);
  int num_c = (int)floorf((float)n_filled * 0.3f);
  int idx = num_c - 1; if (idx < 0) idx = 0;
  float score = filled ? sel[(size_t)b * CELLS + c] : 2.0f;
  int cnt_lt = 0, cnt_le = 0;
  for (int l = 0; l < CELLS; ++l){
    float sv = __shfl(score, l);
    cnt_lt += (sv < score);
    cnt_le += (sv <= score);
  }
  float cand = (active && cnt_lt <= idx && idx < cnt_le) ? score : 3.4e38f;
  for (int off = 32; off; off >>= 1) cand = fminf(cand, __shfl_xor(cand, off));
  float thr = (num_c > 0) ? cand : -1.0f;
  bool corrupt = filled && (score <= thr);
  if (active){
    float rvv[6]; float rsum = 0.f;
#pragma unroll
    for (int ch = 0; ch < 6; ++ch){ rvv[ch] = rv[(size_t)b * (6 * CELLS) + ch * CELLS + c]; rsum += rvv[ch]; }
    float v0 = corrupt ? 0.f : yt0;
    y_neg[(size_t)w * YDIM + c] = v0;
    feat[(size_t)w * FEATP + c] = f2bf(clip01(v0));
#pragma unroll
    for (int ch = 0; ch < 6; ++ch){
      float val = corrupt ? rvv[ch] / rsum : y_true[(size_t)b * YDIM + (ch + 1) * CELLS + c];
      y_neg[(size_t)w * YDIM + (ch + 1) * CELLS + c] = val;
      feat[(size_t)w * FEATP + (ch + 1) * CELLS + c] = f2bf(clip01(val));
    }
  }
}

// e[i] = b3 + sum_x e_part[x][i]
__global__ void k_esum(const float* __restrict__ e_part, const float* __restrict__ b3,
                       float* __restrict__ e_out, int Mc){
  int i = blockIdx.x * blockDim.x + threadIdx.x;
  if (i >= Mc) return;
  float s = b3[0];
#pragma unroll
  for (int x = 0; x < NPART; ++x) s += e_part[(size_t)x * Mc + i];
  e_out[i] = s;
}

// refine update from 2 split-K partials; also refresh feat
__global__ void k_upd(const float* __restrict__ part, float* __restrict__ yneg,
                      ushort_t* __restrict__ feat, int Mc){
  int gid = blockIdx.x * blockDim.x + threadIdx.x;
  int total = Mc * YDIM;
  if (gid >= total) return;
  int i = gid / YDIM, c = gid - i * YDIM;
  float g = part[gid] + part[(size_t)total + gid];
  float y = yneg[gid];
  y = clip01(y + 0.15f * g * clipmask(y));
  yneg[gid] = y;
  feat[(size_t)i * FEATP + c] = f2bf(y);
}

// mse: grid-stride, block-reduce, 1 atomic per block (2 partials)
__global__ __launch_bounds__(256) void k_mse(const float* __restrict__ part, const float* __restrict__ yhat,
                      const float* __restrict__ y_true, const float* __restrict__ sigma_b,
                      double* __restrict__ acc, int Mc){
  int total = Mc * YDIM;
  double v = 0.0;
  for (int gid = blockIdx.x * blockDim.x + threadIdx.x; gid < total; gid += gridDim.x * blockDim.x){
    int i = gid / YDIM;
    float y = yhat[gid];
    float dy = part[gid] + part[(size_t)total + gid];
    float score = dy * clipmask(y);
    float sigma = sigma_b[i];
    float tgt = (y - y_true[gid]) / (sigma + 1e-8f);
    float d = score - tgt;
    v += (double)d * (double)d;
  }
  for (int off = 32; off; off >>= 1) v += __shfl_down(v, off);
  __shared__ double wsum[4];
  int lane = threadIdx.x & 63, wid = threadIdx.x >> 6;
  if (lane == 0) wsum[wid] = v;
  __syncthreads();
  if (threadIdx.x == 0) atomicAdd(&acc[0], (wsum[0] + wsum[1]) + (wsum[2] + wsum[3]));
}

__global__ __launch_bounds__(256) void k_contrast(const float* __restrict__ e_pos, const float* __restrict__ e_neg,
                           double* __restrict__ acc){
  double con = 0.0, reg = 0.0;
  for (int b = blockIdx.x * blockDim.x + threadIdx.x; b < B_TOT; b += gridDim.x * blockDim.x){
    float ep = e_pos[b], en = e_neg[b];
    float a = -ep, bb = -en;
    float m = fmaxf(a, bb);
    float lse = m + logf(expf(a - m) + expf(bb - m));
    con += (double)(ep + lse);
    reg += (double)ep + (double)en;
  }
  for (int off = 32; off; off >>= 1){ con += __shfl_down(con, off); reg += __shfl_down(reg, off); }
  __shared__ double wc[4], wr[4];
  int lane = threadIdx.x & 63, wid = threadIdx.x >> 6;
  if (lane == 0){ wc[wid] = con; wr[wid] = reg; }
  __syncthreads();
  if (threadIdx.x == 0){
    atomicAdd(&acc[1], (wc[0] + wc[1]) + (wc[2] + wc[3]));
    atomicAdd(&acc[2], (wr[0] + wr[1]) + (wr[2] + wr[3]));
  }
}

__global__ void k_finalize(const double* __restrict__ acc, float* __restrict__ out){
  double mse = acc[0] / (double)((long long)B_TOT * YDIM);
  double con = acc[1] / (double)B_TOT;
  double reg = acc[2] / (double)B_TOT;
  out[0] = (float)(mse + con + 0.01 * reg);
}

// ============ 8-phase GEMM, barrier-minimal (2 barriers/K-step) ============
// BM=BN=256, K-step 64, 512 thr = 8 waves (2M x 4N), wave tile 128x64.
// LDS 2x(A[256][64]+B[256][64]) = 128 KiB; x2-unrolled compile-time parity.
// Rows 128B = 8 slots; slot s of row r holds k-chunk (s-r)&7; read slot (chunk+fr)&7.
// Two barriers per K-step: (a) end-of-ph2 releases cur A0/B0 for ph3's t+2 stage;
// (b) end-of-ph3 + boundary vmcnt gates step t+1's reads.
// modes: 0 z1: z=v+b1 -> outA=dgz1=bf(dgelu z), outB=h1=bf(gelu z)
//        1 z2: z=v+b2 -> outB?=dz2=bf(W3*dgelu z); e_part?=row sums gelu(z)*W3
//        2 dz1: v *= bf2f(dgz[o]); outA
#define STG_H(srcPtr, p0, buf, k0, h) \
  _Pragma("unroll") \
  for (int ro_ = 0; ro_ < 2; ++ro_){ \
    int r_ = (ro_ << 7) + ((h) << 6) + (t >> 3); \
    int c_ = ((t & 7) - r_) & 7; \
    load_lds16((const char*)(srcPtr) + (((size_t)((p0) + r_)) * K + (k0) + (c_ << 3)) * 2, \
               (char*)(buf) + (r_ << 7) + ((t & 7) << 4)); \
  }

#define K_STEP(SV, CA_, CB_, NA_, NB_) do { \
  const int s_ = (SV); \
  const int kn1_ = (s_ + 1) << 6, kn2_ = (s_ + 2) << 6; \
  short8v afa[4], afb[4], afc[4], afd[4], bf0[4], bf1[4]; \
  /* ph0: (mh0,kk0); stage B1(s+1) */ \
  _Pragma("unroll") \
  for (int n = 0; n < 4; ++n) bf0[n] = *(const short8v*)((const char*)(CB_) + brow + (n << 11) + aslot0); \
  _Pragma("unroll") \
  for (int m = 0; m < 4; ++m) afa[m] = *(const short8v*)((const char*)(CA_) + arow + (m << 11) + aslot0); \
  if (s_ + 1 < NT){ STG_H(BT, n0, (NB_), kn1_, 1); } \
  __builtin_amdgcn_s_setprio(1); \
  _Pragma("unroll") \
  for (int m = 0; m < 4; ++m) \
    _Pragma("unroll") \
    for (int n = 0; n < 4; ++n) \
      acc[m][n] = __builtin_amdgcn_mfma_f32_16x16x32_bf16(afa[m], bf0[n], acc[m][n], 0, 0, 0); \
  __builtin_amdgcn_s_setprio(0); \
  /* ph1: (mh1,kk0); stage A1(s+1) */ \
  _Pragma("unroll") \
  for (int m = 0; m < 4; ++m) afb[m] = *(const short8v*)((const char*)(CA_) + arow + ((m + 4) << 11) + aslot0); \
  if (s_ + 1 < NT){ STG_H(A, m0, (NA_), kn1_, 1); } \
  __builtin_amdgcn_s_setprio(1); \
  _Pragma("unroll") \
  for (int m = 0; m < 4; ++m) \
    _Pragma("unroll") \
    for (int n = 0; n < 4; ++n) \
      acc[m + 4][n] = __builtin_amdgcn_mfma_f32_16x16x32_bf16(afb[m], bf0[n], acc[m + 4][n], 0, 0, 0); \
  __builtin_amdgcn_s_setprio(0); \
  /* ph2: (mh0,kk1) */ \
  _Pragma("unroll") \
  for (int n = 0; n < 4; ++n) bf1[n] = *(const short8v*)((const char*)(CB_) + brow + (n << 11) + aslot1); \
  _Pragma("unroll") \
  for (int m = 0; m < 4; ++m) afc[m] = *(const short8v*)((const char*)(CA_) + arow + (m << 11) + aslot1); \
  __builtin_amdgcn_s_setprio(1); \
  _Pragma("unroll") \
  for (int m = 0; m < 4; ++m) \
    _Pragma("unroll") \
    for (int n = 0; n < 4; ++n) \
      acc[m][n] = __builtin_amdgcn_mfma_f32_16x16x32_bf16(afc[m], bf1[n], acc[m][n], 0, 0, 0); \
  __builtin_amdgcn_s_setprio(0); \
  asm volatile("s_waitcnt lgkmcnt(0)" ::: "memory"); \
  __builtin_amdgcn_s_barrier();   /* (a) release cur A0/B0 for overwrite */ \
  /* ph3: (mh1,kk1); stage A0+B0(s+2) into cur parity */ \
  _Pragma("unroll") \
  for (int m = 0; m < 4; ++m) afd[m] = *(const short8v*)((const char*)(CA_) + arow + ((m + 4) << 11) + aslot1); \
  if (s_ + 2 < NT){ STG_H(A, m0, (CA_), kn2_, 0); STG_H(BT, n0, (CB_), kn2_, 0); } \
  __builtin_amdgcn_s_setprio(1); \
  _Pragma("unroll") \
  for (int m = 0; m < 4; ++m) \
    _Pragma("unroll") \
    for (int n = 0; n < 4; ++n) \
      acc[m + 4][n] = __builtin_amdgcn_mfma_f32_16x16x32_bf16(afd[m], bf1[n], acc[m + 4][n], 0, 0, 0); \
  __builtin_amdgcn_s_setprio(0); \
  asm volatile("s_waitcnt lgkmcnt(0)" ::: "memory"); \
  if (s_ + 1 < NT){ \
    if (s_ + 2 < NT) asm volatile("s_waitcnt vmcnt(4)" ::: "memory"); \
    else             asm volatile("s_waitcnt vmcnt(0)" ::: "memory"); \
  } \
  __builtin_amdgcn_s_barrier();   /* (b) K-step boundary */ \
} while (0)

__global__ __launch_bounds__(512, 1) void gemm_p(
    const ushort_t* __restrict__ A, const ushort_t* __restrict__ BT,
    int N, int K, int mode,
    const float* __restrict__ bias, const float* __restrict__ W3,
    const ushort_t* __restrict__ dgz,
    ushort_t* __restrict__ outA, ushort_t* __restrict__ outB,
    float* __restrict__ e_part, int Mrows){
  __shared__ __align__(16) ushort_t Al[2][256 * 64];
  __shared__ __align__(16) ushort_t Bl[2][256 * 64];
  const int t = threadIdx.x, lane = t & 63, w = t >> 6;
  int bx = blockIdx.x, by = blockIdx.y;
  xcd_swizzle(gridDim.x, gridDim.y, bx, by);
  const int m0 = by << 8, n0 = bx << 8;
  const int fr = lane & 15, kg = lane >> 4;
  const int wm = w >> 2, wn = w & 3;
  const int NT = K >> 6;
  const int wr = wm << 7, wc = wn << 6;
  const int aslot0 = ((kg + fr) & 7) << 4;        // kk=0: chunk=kg
  const int aslot1 = ((4 + kg + fr) & 7) << 4;    // kk=1: chunk=4+kg
  const int arow = ((wm << 7) + fr) << 7;
  const int brow = ((wn << 6) + fr) << 7;

  float4v acc[8][4];
#pragma unroll
  for (int m = 0; m < 8; ++m)
#pragma unroll
    for (int n = 0; n < 4; ++n) acc[m][n] = (float4v)0.f;

  // prologue: K-step 0 fully, then A0(1),B0(1)
  STG_H(A, m0, &Al[0][0], 0, 0); STG_H(A, m0, &Al[0][0], 0, 1);
  STG_H(BT, n0, &Bl[0][0], 0, 0); STG_H(BT, n0, &Bl[0][0], 0, 1);
  if (NT > 1){ STG_H(A, m0, &Al[1][0], 64, 0); STG_H(BT, n0, &Bl[1][0], 64, 0); }
  if (NT > 1) asm volatile("s_waitcnt vmcnt(4)" ::: "memory");
  else        asm volatile("s_waitcnt vmcnt(0)" ::: "memory");
  __builtin_amdgcn_s_barrier();

  for (int s2 = 0; s2 + 1 < NT; s2 += 2){
    K_STEP(s2,     &Al[0][0], &Bl[0][0], &Al[1][0], &Bl[1][0]);
    K_STEP(s2 + 1, &Al[1][0], &Bl[1][0], &Al[0][0], &Bl[0][0]);
  }
  if (NT & 1) K_STEP(NT - 1, &Al[0][0], &Bl[0][0], &Al[1][0], &Bl[1][0]);

  // ---- epilogue: per-wave f32 LDS slice -> coalesced 16B bf16 stores ----
  float* slice = (float*)&Al[0][0] + w * (16 * 68);
  float* e_lds = (float*)&Bl[0][0];
  const bool do_e = (mode == 1) && (e_part != nullptr);
  if (do_e){
    if (t < 256) e_lds[t] = 0.f;
    __syncthreads();
  }
  const int rrow = lane >> 2;      // 0..15
  const int rq = lane & 3;         // 16-col group
#pragma unroll
  for (int m = 0; m < 8; ++m){
    if (m) asm volatile("s_waitcnt lgkmcnt(0)" ::: "memory");  // prior reads done before overwrite
#pragma unroll
    for (int j = 0; j < 4; ++j)
#pragma unroll
      for (int n = 0; n < 4; ++n)
        slice[((kg << 2) + j) * 68 + (n << 4) + fr] = acc[m][n][j];
    asm volatile("s_waitcnt lgkmcnt(0)" ::: "memory");
    const int grow = m0 + wr + (m << 4) + rrow;
    const int gcol = n0 + wc + (rq << 4);
    float val[16];
#pragma unroll
    for (int p2 = 0; p2 < 4; ++p2){
      float4 vv = *(const float4*)&slice[rrow * 68 + (rq << 4) + (p2 << 2)];
      val[p2 * 4 + 0] = vv.x; val[p2 * 4 + 1] = vv.y;
      val[p2 * 4 + 2] = vv.z; val[p2 * 4 + 3] = vv.w;
    }
    const size_t ob = (size_t)grow * N + gcol;
    if (mode == 0){
      float o0[16], o1[16];
#pragma unroll
      for (int e = 0; e < 16; ++e){
        float z = val[e] + bias[gcol + e];
        o0[e] = dgelu_f(z);
        o1[e] = gelu_f(z);
      }
      store16(outA + ob, o0);
      store16(outB + ob, o1);
    } else if (mode == 1){
      float pe = 0.f;
      float o0[16];
#pragma unroll
      for (int e = 0; e < 16; ++e){
        float z = val[e] + bias[gcol + e];
        float w3 = W3[gcol + e];
        o0[e] = w3 * dgelu_f(z);
        if (do_e) pe += gelu_f(z) * w3;
      }
      if (outB) store16(outB + ob, o0);
      if (do_e){
        pe += __shfl_xor(pe, 1);
        pe += __shfl_xor(pe, 2);
        if (rq == 0) atomicAdd(&e_lds[wr + (m << 4) + rrow], pe);
      }
    } else {
      float o0[16];
      short8v g0 = *(const short8v*)&dgz[ob];
      short8v g1 = *(const short8v*)&dgz[ob + 8];
#pragma unroll
      for (int e = 0; e < 8; ++e){
        o0[e]     = val[e]     * bf2f((ushort_t)g0[e]);
        o0[8 + e] = val[8 + e] * bf2f((ushort_t)g1[e]);
      }
      store16(outA + ob, o0);
    }
  }
  if (do_e){
    __syncthreads();
    if (t < 256) e_part[(size_t)bx * Mrows + m0 + t] = e_lds[t];
  }
}

// ============ dy GEMM: 128x128 tile, split-K x2 (grid 2 x Mc/128 x 2 = 512 blocks,
// ============ exactly 2 blocks/CU at 64 KB LDS; K=1024/block) ============
#define DY_STAGE(Asl_, Bsl_, k0_) do { \
  _Pragma("unroll") \
  for (int i_ = 0; i_ < 4; ++i_){ \
    int c_ = i_ * 4 + w; \
    int r_ = c_ * 8 + rsub; \
    load_lds16((const char*)A + ((size_t)(m0 + r_) * K + (k0_)) * 2 + cb, (char*)(Asl_) + c_ * 1024 + lane * 16); \
    load_lds16((const char*)BT + ((size_t)(n0 + r_) * K + (k0_)) * 2 + cb, (char*)(Bsl_) + c_ * 1024 + lane * 16); \
  } } while (0)

#define DY_MFMA(Asl_, Bsl_) do { \
  _Pragma("unroll") \
  for (int kk = 0; kk < 2; ++kk){ \
    int kb = kk * 32 + kg * 8; \
    short8v a[4], b[4]; \
    _Pragma("unroll") \
    for (int m = 0; m < 4; ++m) a[m] = *(const short8v*)&(Asl_)[(wr + m * 16 + fr) * 64 + kb]; \
    _Pragma("unroll") \
    for (int n = 0; n < 4; ++n) b[n] = *(const short8v*)&(Bsl_)[(wc + n * 16 + fr) * 64 + kb]; \
    _Pragma("unroll") \
    for (int m = 0; m < 4; ++m) \
      _Pragma("unroll") \
      for (int n = 0; n < 4; ++n) \
        acc[m][n] = __builtin_amdgcn_mfma_f32_16x16x32_bf16(a[m], b[n], acc[m][n], 0, 0, 0); \
  } } while (0)

__global__ __launch_bounds__(256) void gemm_dy4(
    const ushort_t* __restrict__ A, const ushort_t* __restrict__ BT,
    float* __restrict__ part, int Mc){
  __shared__ __align__(16) ushort_t Asl[2][128 * 64];
  __shared__ __align__(16) ushort_t Bsl[2][128 * 64];
  const int K = HDIM;
  const int t = threadIdx.x, lane = t & 63, w = t >> 6;
  int bx = blockIdx.x, by = blockIdx.y;
  xcd_swizzle(gridDim.x, gridDim.y, bx, by);
  const int m0 = by << 7, n0 = bx << 7;
  const int ks = blockIdx.z;
  const int kbeg = ks << 10, kend = kbeg + 1024;
  const int fr = lane & 15, kg = lane >> 4;
  const int rsub = lane >> 3;
  const int cb = (lane & 7) * 16;
  const int wr = (w >> 1) * 64, wc = (w & 1) * 64;

  float4v acc[4][4];
#pragma unroll
  for (int m = 0; m < 4; ++m)
#pragma unroll
    for (int n = 0; n < 4; ++n) acc[m][n] = (float4v)0.f;

  DY_STAGE(Asl[0], Bsl[0], kbeg);
  __syncthreads();
  int cur = 0;
  for (int k0 = kbeg; k0 < kend; k0 += 64){
    if (k0 + 64 < kend) DY_STAGE(Asl[cur ^ 1], Bsl[cur ^ 1], k0 + 64);
    DY_MFMA(Asl[cur], Bsl[cur]);
    __syncthreads();
    cur ^= 1;
  }

  float* pp = part + (size_t)ks * Mc * YDIM;
#pragma unroll
  for (int m = 0; m < 4; ++m){
#pragma unroll
    for (int j = 0; j < 4; ++j){
      int row = m0 + wr + m * 16 + kg * 4 + j;
#pragma unroll
      for (int n = 0; n < 4; ++n){
        int col = n0 + wc + n * 16 + fr;
        if (col < YDIM) pp[(size_t)row * YDIM + col] = acc[m][n][j];
      }
    }
  }
}

// ---------------- host ----------------
static inline char* carve(char*& p, size_t bytes){
  char* r = p; p += (bytes + 255) & ~(size_t)255; return r;
}

extern "C" void kernel_launch(void* const* d_in, const int* in_sizes, int n_in,
                              void* d_out, int out_size, void* d_ws, size_t ws_size,
                              hipStream_t stream){
  (void)in_sizes; (void)n_in; (void)out_size;
  const float* y_true  = (const float*)d_in[0];
  const float* cond    = (const float*)d_in[1];
  const int*   k_idx   = (const int*)d_in[2];
  const float* eps_pos = (const float*)d_in[3];
  const float* eps_neg = (const float*)d_in[4];
  const float* sel     = (const float*)d_in[5];
  const float* rv      = (const float*)d_in[6];
  const float* W1      = (const float*)d_in[7];
  const float* b1      = (const float*)d_in[8];
  const float* W2      = (const float*)d_in[9];
  const float* b2      = (const float*)d_in[10];
  const float* W3      = (const float*)d_in[11];
  const float* b3      = (const float*)d_in[12];
  const float* k_emb   = (const float*)d_in[13];

  char* p = (char*)d_ws;
  double* accs   = (double*)carve(p, 3 * sizeof(double));
  float* sigma_b = (float*)carve(p, (size_t)B_TOT * 4);
  float* e_pos   = (float*)carve(p, (size_t)B_TOT * 4);
  float* e_neg   = (float*)carve(p, (size_t)B_TOT * 4);
  ushort_t* W1bf = (ushort_t*)carve(p, (size_t)256 * HDIM * 2);   // rows 0..255 of W1 (dy B^T)
  ushort_t* W1T  = (ushort_t*)carve(p, (size_t)HDIM * FEATP * 2);
  ushort_t* W2bf = (ushort_t*)carve(p, (size_t)HDIM * HDIM * 2);
  ushort_t* W2T  = (ushort_t*)carve(p, (size_t)HDIM * HDIM * 2);
  size_t fixed = (size_t)(p - (char*)d_ws);

  // per sample: feat 896 + 3 H-planes (dgz1,h1,dz2) 12288 + e_part 32 + yhat/yneg 2016
  // dy partials (2 x 252 f32 = 2016 B) alias dgz1 (dead after the dz1-GEMM read it).
  const size_t per_sample = FEATP * 2 + 3 * HDIM * 2 + NPART * 4 + 2 * YDIM * 4;
  int Mc = B_TOT;
  while (Mc > 256 && fixed + (size_t)Mc * per_sample + 65536 > ws_size) Mc >>= 1;

  ushort_t* feat = (ushort_t*)carve(p, (size_t)Mc * FEATP * 2);
  ushort_t* dgz1 = (ushort_t*)carve(p, (size_t)Mc * HDIM * 2);
  ushort_t* h1   = (ushort_t*)carve(p, (size_t)Mc * HDIM * 2);
  ushort_t* dz2  = (ushort_t*)carve(p, (size_t)Mc * HDIM * 2);
  float* e_part  = (float*)carve(p, (size_t)Mc * NPART * 4);
  float* yhat    = (float*)carve(p, (size_t)Mc * YDIM * 4);
  float* yneg    = (float*)carve(p, (size_t)Mc * YDIM * 4);
  ushort_t* dz1  = h1;          // alias: h1 dead once the z2-GEMM consumed it
  float* part    = (float*)dgz1; // alias: dgz1 dead once the dz1-GEMM consumed it

  dim3 blk(256);
  k_zero_acc<<<1, 1, 0, stream>>>(accs);
  k_sigma<<<(B_TOT + 255) / 256, blk, 0, stream>>>(k_idx, sigma_b);
  k_cast<<<(256 * HDIM + 255) / 256, blk, 0, stream>>>(W1, W1bf, 256 * HDIM);
  k_w1t<<<(HDIM * FEATP + 255) / 256, blk, 0, stream>>>(W1, W1T);
  k_w2x<<<dim3(HDIM / 32, HDIM / 32), blk, 0, stream>>>(W2, W2bf, W2T);

  auto G = [&](const ushort_t* Ap, const ushort_t* BTp, int K, int mode,
               const float* biasp, ushort_t* oA, ushort_t* oB, float* ep){
    gemm_p<<<dim3(HDIM / 256, Mc / 256), dim3(512), 0, stream>>>(
        Ap, BTp, HDIM, K, mode, biasp, W3, dgz1, oA, oB, ep, Mc);
  };
  auto Gdy = [&](){
    gemm_dy4<<<dim3(2, Mc / 128, 2), blk, 0, stream>>>(dz1, W1bf, part, Mc);
  };

  int nCh = B_TOT / Mc;
  for (int c = 0; c < nCh; ++c){
    int b0 = c * Mc;
    k_feat_static<<<(Mc * 196 + 255) / 256, blk, 0, stream>>>(
        cond + (size_t)b0 * CELLS, k_emb, k_idx + b0, feat, Mc);

    // ---- positive branch
    k_noise<<<(Mc * CELLS + 255) / 256, blk, 0, stream>>>(
        y_true + (size_t)b0 * YDIM, eps_pos + (size_t)b0 * YDIM, sigma_b + b0, yhat, feat, Mc);
    G(feat, W1T, FEATP, 0, b1, dgz1, h1, nullptr);
    G(h1, W2T, HDIM, 1, b2, nullptr, dz2, e_part);
    k_esum<<<(Mc + 255) / 256, blk, 0, stream>>>(e_part, b3, e_pos + b0, Mc);
    G(dz2, W2bf, HDIM, 2, nullptr, dz1, nullptr, nullptr);
    Gdy();
    k_mse<<<512, blk, 0, stream>>>(part, yhat, y_true + (size_t)b0 * YDIM, sigma_b + b0, accs, Mc);

    // ---- negative branch
    k_makeneg<<<(Mc * 64 + 255) / 256, blk, 0, stream>>>(y_true, sel, rv, yneg, feat, b0, Mc);
    for (int r = 0; r < 5; ++r){
      G(feat, W1T, FEATP, 0, b1, dgz1, h1, nullptr);
      G(h1, W2T, HDIM, 1, b2, nullptr, dz2, nullptr);
      G(dz2, W2bf, HDIM, 2, nullptr, dz1, nullptr, nullptr);
      Gdy();
      k_upd<<<(Mc * YDIM + 255) / 256, blk, 0, stream>>>(part, yneg, feat, Mc);
    }
    k_noise<<<(Mc * CELLS + 255) / 256, blk, 0, stream>>>(
        yneg, eps_neg + (size_t)b0 * YDIM, sigma_b + b0, yhat, feat, Mc);
    G(feat, W1T, FEATP, 0, b1, dgz1, h1, nullptr);
    G(h1, W2T, HDIM, 1, b2, nullptr, nullptr, e_part);
    k_esum<<<(Mc + 255) / 256, blk, 0, stream>>>(e_part, b3, e_neg + b0, Mc);
  }

  k_contrast<<<64, blk, 0, stream>>>(e_pos, e_neg, accs);
  k_finalize<<<1, 1, 0, stream>>>(accs, (float*)d_out);
}

// Round 14
// 2889.954 us; speedup vs baseline: 1.0245x; 1.0245x over previous
//
#include <hip/hip_runtime.h>
#include <math.h>

#define B_TOT 16384
#define CELLS 36
#define YDIM 252       // 7*6*6
#define FEATP 448      // 416 padded to 448
#define FEAT_REAL 416
#define HDIM 2048
#define EMB_DIM 128
#define KSTEPS 50
#define NPART 8        // e_part slabs = HDIM/256

typedef unsigned short ushort_t;
typedef __attribute__((ext_vector_type(8))) short short8v;
typedef __attribute__((ext_vector_type(4))) float float4v;

__device__ __forceinline__ float clip01(float x){ return fminf(fmaxf(x, 0.f), 1.f); }
__device__ __forceinline__ float tanh_fast(float u){
  float e = __expf(2.f * u);
  return 1.f - 2.f / (e + 1.f);
}
__device__ __forceinline__ float gelu_f(float x){
  float u = 0.7978845608028654f * (x + 0.044715f * x * x * x);
  return 0.5f * x * (1.f + tanh_fast(u));
}
__device__ __forceinline__ float dgelu_f(float x){
  float x2 = x * x;
  float u = 0.7978845608028654f * (x + 0.044715f * x2 * x);
  float t = tanh_fast(u);
  return 0.5f * (1.f + t) + 0.5f * x * (1.f - t * t) * 0.7978845608028654f * (1.f + 0.134145f * x2);
}
__device__ __forceinline__ float clipmask(float y){ return (y == 0.f || y == 1.f) ? 0.5f : 1.f; }
__device__ __forceinline__ ushort_t f2bf(float x){
  union { float f; unsigned u; } v; v.f = x;
  unsigned r = v.u + 0x7fffu + ((v.u >> 16) & 1u);
  return (ushort_t)(r >> 16);
}
__device__ __forceinline__ float bf2f(ushort_t h){
  union { unsigned u; float f; } v; v.u = ((unsigned)h) << 16; return v.f;
}
__device__ __forceinline__ void load_lds16(const void* g, void* l){
  __builtin_amdgcn_global_load_lds((const __attribute__((address_space(1))) unsigned int*)g,
                                   (__attribute__((address_space(3))) unsigned int*)l, 16, 0, 0);
}
__device__ __forceinline__ void store16(ushort_t* dst, const float* x){
  short8v r0, r1;
#pragma unroll
  for (int i = 0; i < 8; ++i){ r0[i] = (short)f2bf(x[i]); r1[i] = (short)f2bf(x[8 + i]); }
  *(short8v*)dst = r0;
  *(short8v*)&dst[8] = r1;
}
// m204 bijective XCD swizzle
__device__ __forceinline__ void xcd_swizzle(int GX, int GY, int& bx, int& by){
  int nwg = GX * GY;
  int orig = by * GX + bx;
  int q = nwg >> 3, r = nwg & 7;
  int xcd = orig & 7, loc = orig >> 3;
  int lin = (xcd < r ? xcd * (q + 1) : r * (q + 1) + (xcd - r) * q) + loc;
  bx = lin % GX; by = lin / GX;
}

// ---------------- small kernels ----------------
__global__ void k_zero_acc(double* acc){ acc[0] = 0.0; acc[1] = 0.0; acc[2] = 0.0; }

__global__ void k_sigma(const int* __restrict__ k_idx, float* __restrict__ sigma_b){
  int b = blockIdx.x * blockDim.x + threadIdx.x;
  if (b >= B_TOT) return;
  int i = (KSTEPS - 1) - k_idx[b];
  float t = (float)i / (float)(KSTEPS - 1);
  float ang = (1.f - t) * 1.57079632679489662f;
  float c = cosf(ang);
  sigma_b[b] = 0.01f + 0.94f * c * c;
}

__global__ void k_cast(const float* __restrict__ in, ushort_t* __restrict__ out, int n){
  int gid = blockIdx.x * blockDim.x + threadIdx.x;
  if (gid < n) out[gid] = f2bf(in[gid]);
}
// W1T[h][f] (f padded to 448)
__global__ void k_w1t(const float* __restrict__ W1, ushort_t* __restrict__ W1T){
  int gid = blockIdx.x * blockDim.x + threadIdx.x;
  if (gid >= HDIM * FEATP) return;
  int h = gid / FEATP, f = gid - h * FEATP;
  W1T[gid] = (f < FEAT_REAL) ? f2bf(W1[(size_t)f * HDIM + h]) : (ushort_t)0;
}
// merged: W2bf = cast(W2) (row-major), W2T[n][k] = W2[k][n] — one read of W2
__global__ __launch_bounds__(256) void k_w2x(const float* __restrict__ W2,
                                             ushort_t* __restrict__ W2bf,
                                             ushort_t* __restrict__ W2T){
  __shared__ float tile[32][33];
  int x0 = blockIdx.x << 5, y0 = blockIdx.y << 5;
  int tx = threadIdx.x & 31, ty = threadIdx.x >> 5;
#pragma unroll
  for (int i = 0; i < 4; ++i){
    float v = W2[(size_t)(y0 + ty + i * 8) * HDIM + (x0 + tx)];
    tile[ty + i * 8][tx] = v;
    W2bf[(size_t)(y0 + ty + i * 8) * HDIM + (x0 + tx)] = f2bf(v);
  }
  __syncthreads();
#pragma unroll
  for (int i = 0; i < 4; ++i)
    W2T[(size_t)(x0 + ty + i * 8) * HDIM + (y0 + tx)] = f2bf(tile[tx][ty + i * 8]);
}

// static cols of feat: 252..447 (cond, emb, zero pad)
__global__ void k_feat_static(const float* __restrict__ cond, const float* __restrict__ k_emb,
                              const int* __restrict__ k_idx, ushort_t* __restrict__ feat, int Mc){
  int gid = blockIdx.x * blockDim.x + threadIdx.x;
  if (gid >= Mc * 196) return;
  int i = gid / 196, c = gid - i * 196;
  float v;
  if (c < CELLS)            v = cond[(size_t)i * CELLS + c];
  else if (c < CELLS + EMB_DIM) v = k_emb[(size_t)k_idx[i] * EMB_DIM + (c - CELLS)];
  else                      v = 0.f;
  feat[(size_t)i * FEATP + YDIM + c] = f2bf(v);
}

// noise + direct feat write
__global__ void k_noise(const float* __restrict__ y, const float* __restrict__ eps,
                        const float* __restrict__ sigma_b, float* __restrict__ out,
                        ushort_t* __restrict__ feat, int Mc){
  int gid = blockIdx.x * blockDim.x + threadIdx.x;
  if (gid >= Mc * CELLS) return;
  int i = gid / CELLS, cell = gid - i * CELLS;
  float sigma = sigma_b[i];
  float sq = sqrtf(fmaxf(1.f - sigma * sigma, 1e-8f));
  const float* yp = y + (size_t)i * YDIM + cell;
  const float* ep = eps + (size_t)i * YDIM + cell;
  float yh[7];
#pragma unroll
  for (int ch = 0; ch < 7; ++ch){
    float e = ep[ch * CELLS] * 0.1f;
    yh[ch] = clip01(sq * yp[ch * CELLS] + sigma * e);
  }
  bool filled = yh[0] > 0.5f;
  float s = 0.f;
#pragma unroll
  for (int ch = 1; ch < 7; ++ch) s += yh[ch];
  float* op = out + (size_t)i * YDIM + cell;
  ushort_t* fp = feat + (size_t)i * FEATP + cell;
  op[0] = yh[0];
  fp[0] = f2bf(yh[0]);
#pragma unroll
  for (int ch = 1; ch < 7; ++ch){
    float v = yh[ch];
    if (filled) v = v / (s + 1e-8f);
    v = clip01(v);
    op[ch * CELLS] = v;
    fp[ch * CELLS] = f2bf(v);
  }
}

// y_neg init + feat write
__global__ void k_makeneg(const float* __restrict__ y_true, const float* __restrict__ sel,
                          const float* __restrict__ rv, float* __restrict__ y_neg,
                          ushort_t* __restrict__ feat, int b0, int Mc){
  int w = (blockIdx.x * blockDim.x + threadIdx.x) >> 6;
  int lane = threadIdx.x & 63;
  if (w >= Mc) return;
  int b = b0 + w;
  int c = lane;
  bool active = c < CELLS;
  float yt0 = active ? y_true[(size_t)b * YDIM + c] : 0.f;
  bool filled = active && (yt0 > 0.5f);
  unsigned long long bal = __ballot(filled);
  int n_filled = __popcll(bal);
  int num_c = (int)floorf((float)n_filled * 0.3f);
  int idx = num_c - 1; if (idx < 0) idx = 0;
  float score = filled ? sel[(size_t)b * CELLS + c] : 2.0f;
  int cnt_lt = 0, cnt_le = 0;
  for (int l = 0; l < CELLS; ++l){
    float sv = __shfl(score, l);
    cnt_lt += (sv < score);
    cnt_le += (sv <= score);
  }
  float cand = (active && cnt_lt <= idx && idx < cnt_le) ? score : 3.4e38f;
  for (int off = 32; off; off >>= 1) cand = fminf(cand, __shfl_xor(cand, off));
  float thr = (num_c > 0) ? cand : -1.0f;
  bool corrupt = filled && (score <= thr);
  if (active){
    float rvv[6]; float rsum = 0.f;
#pragma unroll
    for (int ch = 0; ch < 6; ++ch){ rvv[ch] = rv[(size_t)b * (6 * CELLS) + ch * CELLS + c]; rsum += rvv[ch]; }
    float v0 = corrupt ? 0.f : yt0;
    y_neg[(size_t)w * YDIM + c] = v0;
    feat[(size_t)w * FEATP + c] = f2bf(clip01(v0));
#pragma unroll
    for (int ch = 0; ch < 6; ++ch){
      float val = corrupt ? rvv[ch] / rsum : y_true[(size_t)b * YDIM + (ch + 1) * CELLS + c];
      y_neg[(size_t)w * YDIM + (ch + 1) * CELLS + c] = val;
      feat[(size_t)w * FEATP + (ch + 1) * CELLS + c] = f2bf(clip01(val));
    }
  }
}

// e[i] = b3 + sum_x e_part[x][i]
__global__ void k_esum(const float* __restrict__ e_part, const float* __restrict__ b3,
                       float* __restrict__ e_out, int Mc){
  int i = blockIdx.x * blockDim.x + threadIdx.x;
  if (i >= Mc) return;
  float s = b3[0];
#pragma unroll
  for (int x = 0; x < NPART; ++x) s += e_part[(size_t)x * Mc + i];
  e_out[i] = s;
}

// refine update from 4 split-K partials; also refresh feat
__global__ void k_upd(const float* __restrict__ part, float* __restrict__ yneg,
                      ushort_t* __restrict__ feat, int Mc){
  int gid = blockIdx.x * blockDim.x + threadIdx.x;
  int total = Mc * YDIM;
  if (gid >= total) return;
  int i = gid / YDIM, c = gid - i * YDIM;
  float g = ((part[gid] + part[(size_t)total + gid]) +
             (part[2 * (size_t)total + gid] + part[3 * (size_t)total + gid]));
  float y = yneg[gid];
  y = clip01(y + 0.15f * g * clipmask(y));
  yneg[gid] = y;
  feat[(size_t)i * FEATP + c] = f2bf(y);
}

// mse: grid-stride, block-reduce, 1 atomic per block (4 partials)
__global__ __launch_bounds__(256) void k_mse(const float* __restrict__ part, const float* __restrict__ yhat,
                      const float* __restrict__ y_true, const float* __restrict__ sigma_b,
                      double* __restrict__ acc, int Mc){
  int total = Mc * YDIM;
  double v = 0.0;
  for (int gid = blockIdx.x * blockDim.x + threadIdx.x; gid < total; gid += gridDim.x * blockDim.x){
    int i = gid / YDIM;
    float y = yhat[gid];
    float dy = ((part[gid] + part[(size_t)total + gid]) +
                (part[2 * (size_t)total + gid] + part[3 * (size_t)total + gid]));
    float score = dy * clipmask(y);
    float sigma = sigma_b[i];
    float tgt = (y - y_true[gid]) / (sigma + 1e-8f);
    float d = score - tgt;
    v += (double)d * (double)d;
  }
  for (int off = 32; off; off >>= 1) v += __shfl_down(v, off);
  __shared__ double wsum[4];
  int lane = threadIdx.x & 63, wid = threadIdx.x >> 6;
  if (lane == 0) wsum[wid] = v;
  __syncthreads();
  if (threadIdx.x == 0) atomicAdd(&acc[0], (wsum[0] + wsum[1]) + (wsum[2] + wsum[3]));
}

__global__ __launch_bounds__(256) void k_contrast(const float* __restrict__ e_pos, const float* __restrict__ e_neg,
                           double* __restrict__ acc){
  double con = 0.0, reg = 0.0;
  for (int b = blockIdx.x * blockDim.x + threadIdx.x; b < B_TOT; b += gridDim.x * blockDim.x){
    float ep = e_pos[b], en = e_neg[b];
    float a = -ep, bb = -en;
    float m = fmaxf(a, bb);
    float lse = m + logf(expf(a - m) + expf(bb - m));
    con += (double)(ep + lse);
    reg += (double)ep + (double)en;
  }
  for (int off = 32; off; off >>= 1){ con += __shfl_down(con, off); reg += __shfl_down(reg, off); }
  __shared__ double wc[4], wr[4];
  int lane = threadIdx.x & 63, wid = threadIdx.x >> 6;
  if (lane == 0){ wc[wid] = con; wr[wid] = reg; }
  __syncthreads();
  if (threadIdx.x == 0){
    atomicAdd(&acc[1], (wc[0] + wc[1]) + (wc[2] + wc[3]));
    atomicAdd(&acc[2], (wr[0] + wr[1]) + (wr[2] + wr[3]));
  }
}

__global__ void k_finalize(const double* __restrict__ acc, float* __restrict__ out){
  double mse = acc[0] / (double)((long long)B_TOT * YDIM);
  double con = acc[1] / (double)B_TOT;
  double reg = acc[2] / (double)B_TOT;
  out[0] = (float)(mse + con + 0.01 * reg);
}

// ============ 8-phase GEMM, barrier-minimal (2 barriers/K-step) ============
// BM=BN=256, K-step 64, 512 thr = 8 waves (2M x 4N), wave tile 128x64.
// LDS 2x(A[256][64]+B[256][64]) = 128 KiB; x2-unrolled compile-time parity.
// Rows 128B = 8 slots; slot s of row r holds k-chunk (s-r)&7; read slot (chunk+fr)&7.
// Two barriers per K-step: (a) end-of-ph2 releases cur A0/B0 for ph3's t+2 stage;
// (b) end-of-ph3 + boundary vmcnt gates step t+1's reads.
// modes: 0 z1: z=v+b1 -> outA=dgz1=bf(dgelu z), outB=h1=bf(gelu z)
//        1 z2: z=v+b2 -> outB?=dz2=bf(W3*dgelu z); e_part?=row sums gelu(z)*W3
//        2 dz1: v *= bf2f(dgz[o]); outA
#define STG_H(srcPtr, p0, buf, k0, h) \
  _Pragma("unroll") \
  for (int ro_ = 0; ro_ < 2; ++ro_){ \
    int r_ = (ro_ << 7) + ((h) << 6) + (t >> 3); \
    int c_ = ((t & 7) - r_) & 7; \
    load_lds16((const char*)(srcPtr) + (((size_t)((p0) + r_)) * K + (k0) + (c_ << 3)) * 2, \
               (char*)(buf) + (r_ << 7) + ((t & 7) << 4)); \
  }

#define K_STEP(SV, CA_, CB_, NA_, NB_) do { \
  const int s_ = (SV); \
  const int kn1_ = (s_ + 1) << 6, kn2_ = (s_ + 2) << 6; \
  short8v afa[4], afb[4], afc[4], afd[4], bf0[4], bf1[4]; \
  /* ph0: (mh0,kk0); stage B1(s+1) */ \
  _Pragma("unroll") \
  for (int n = 0; n < 4; ++n) bf0[n] = *(const short8v*)((const char*)(CB_) + brow + (n << 11) + aslot0); \
  _Pragma("unroll") \
  for (int m = 0; m < 4; ++m) afa[m] = *(const short8v*)((const char*)(CA_) + arow + (m << 11) + aslot0); \
  if (s_ + 1 < NT){ STG_H(BT, n0, (NB_), kn1_, 1); } \
  __builtin_amdgcn_s_setprio(1); \
  _Pragma("unroll") \
  for (int m = 0; m < 4; ++m) \
    _Pragma("unroll") \
    for (int n = 0; n < 4; ++n) \
      acc[m][n] = __builtin_amdgcn_mfma_f32_16x16x32_bf16(afa[m], bf0[n], acc[m][n], 0, 0, 0); \
  __builtin_amdgcn_s_setprio(0); \
  /* ph1: (mh1,kk0); stage A1(s+1) */ \
  _Pragma("unroll") \
  for (int m = 0; m < 4; ++m) afb[m] = *(const short8v*)((const char*)(CA_) + arow + ((m + 4) << 11) + aslot0); \
  if (s_ + 1 < NT){ STG_H(A, m0, (NA_), kn1_, 1); } \
  __builtin_amdgcn_s_setprio(1); \
  _Pragma("unroll") \
  for (int m = 0; m < 4; ++m) \
    _Pragma("unroll") \
    for (int n = 0; n < 4; ++n) \
      acc[m + 4][n] = __builtin_amdgcn_mfma_f32_16x16x32_bf16(afb[m], bf0[n], acc[m + 4][n], 0, 0, 0); \
  __builtin_amdgcn_s_setprio(0); \
  /* ph2: (mh0,kk1) */ \
  _Pragma("unroll") \
  for (int n = 0; n < 4; ++n) bf1[n] = *(const short8v*)((const char*)(CB_) + brow + (n << 11) + aslot1); \
  _Pragma("unroll") \
  for (int m = 0; m < 4; ++m) afc[m] = *(const short8v*)((const char*)(CA_) + arow + (m << 11) + aslot1); \
  __builtin_amdgcn_s_setprio(1); \
  _Pragma("unroll") \
  for (int m = 0; m < 4; ++m) \
    _Pragma("unroll") \
    for (int n = 0; n < 4; ++n) \
      acc[m][n] = __builtin_amdgcn_mfma_f32_16x16x32_bf16(afc[m], bf1[n], acc[m][n], 0, 0, 0); \
  __builtin_amdgcn_s_setprio(0); \
  asm volatile("s_waitcnt lgkmcnt(0)" ::: "memory"); \
  __builtin_amdgcn_s_barrier();   /* (a) release cur A0/B0 for overwrite */ \
  /* ph3: (mh1,kk1); stage A0+B0(s+2) into cur parity */ \
  _Pragma("unroll") \
  for (int m = 0; m < 4; ++m) afd[m] = *(const short8v*)((const char*)(CA_) + arow + ((m + 4) << 11) + aslot1); \
  if (s_ + 2 < NT){ STG_H(A, m0, (CA_), kn2_, 0); STG_H(BT, n0, (CB_), kn2_, 0); } \
  __builtin_amdgcn_s_setprio(1); \
  _Pragma("unroll") \
  for (int m = 0; m < 4; ++m) \
    _Pragma("unroll") \
    for (int n = 0; n < 4; ++n) \
      acc[m + 4][n] = __builtin_amdgcn_mfma_f32_16x16x32_bf16(afd[m], bf1[n], acc[m + 4][n], 0, 0, 0); \
  __builtin_amdgcn_s_setprio(0); \
  asm volatile("s_waitcnt lgkmcnt(0)" ::: "memory"); \
  if (s_ + 1 < NT){ \
    if (s_ + 2 < NT) asm volatile("s_waitcnt vmcnt(4)" ::: "memory"); \
    else             asm volatile("s_waitcnt vmcnt(0)" ::: "memory"); \
  } \
  __builtin_amdgcn_s_barrier();   /* (b) K-step boundary */ \
} while (0)

__global__ __launch_bounds__(512, 1) void gemm_p(
    const ushort_t* __restrict__ A, const ushort_t* __restrict__ BT,
    int N, int K, int mode,
    const float* __restrict__ bias, const float* __restrict__ W3,
    const ushort_t* __restrict__ dgz,
    ushort_t* __restrict__ outA, ushort_t* __restrict__ outB,
    float* __restrict__ e_part, int Mrows){
  __shared__ __align__(16) ushort_t Al[2][256 * 64];
  __shared__ __align__(16) ushort_t Bl[2][256 * 64];
  const int t = threadIdx.x, lane = t & 63, w = t >> 6;
  int bx = blockIdx.x, by = blockIdx.y;
  xcd_swizzle(gridDim.x, gridDim.y, bx, by);
  const int m0 = by << 8, n0 = bx << 8;
  const int fr = lane & 15, kg = lane >> 4;
  const int wm = w >> 2, wn = w & 3;
  const int NT = K >> 6;
  const int wr = wm << 7, wc = wn << 6;
  const int aslot0 = ((kg + fr) & 7) << 4;        // kk=0: chunk=kg
  const int aslot1 = ((4 + kg + fr) & 7) << 4;    // kk=1: chunk=4+kg
  const int arow = ((wm << 7) + fr) << 7;
  const int brow = ((wn << 6) + fr) << 7;

  float4v acc[8][4];
#pragma unroll
  for (int m = 0; m < 8; ++m)
#pragma unroll
    for (int n = 0; n < 4; ++n) acc[m][n] = (float4v)0.f;

  // prologue: K-step 0 fully, then A0(1),B0(1)
  STG_H(A, m0, &Al[0][0], 0, 0); STG_H(A, m0, &Al[0][0], 0, 1);
  STG_H(BT, n0, &Bl[0][0], 0, 0); STG_H(BT, n0, &Bl[0][0], 0, 1);
  if (NT > 1){ STG_H(A, m0, &Al[1][0], 64, 0); STG_H(BT, n0, &Bl[1][0], 64, 0); }
  if (NT > 1) asm volatile("s_waitcnt vmcnt(4)" ::: "memory");
  else        asm volatile("s_waitcnt vmcnt(0)" ::: "memory");
  __builtin_amdgcn_s_barrier();

  for (int s2 = 0; s2 + 1 < NT; s2 += 2){
    K_STEP(s2,     &Al[0][0], &Bl[0][0], &Al[1][0], &Bl[1][0]);
    K_STEP(s2 + 1, &Al[1][0], &Bl[1][0], &Al[0][0], &Bl[0][0]);
  }
  if (NT & 1) K_STEP(NT - 1, &Al[0][0], &Bl[0][0], &Al[1][0], &Bl[1][0]);

  // ---- epilogue: per-wave f32 LDS slice -> coalesced 16B bf16 stores ----
  float* slice = (float*)&Al[0][0] + w * (16 * 68);
  float* e_lds = (float*)&Bl[0][0];
  const bool do_e = (mode == 1) && (e_part != nullptr);
  if (do_e){
    if (t < 256) e_lds[t] = 0.f;
    __syncthreads();
  }
  const int rrow = lane >> 2;      // 0..15
  const int rq = lane & 3;         // 16-col group
#pragma unroll
  for (int m = 0; m < 8; ++m){
    if (m) asm volatile("s_waitcnt lgkmcnt(0)" ::: "memory");  // prior reads done before overwrite
#pragma unroll
    for (int j = 0; j < 4; ++j)
#pragma unroll
      for (int n = 0; n < 4; ++n)
        slice[((kg << 2) + j) * 68 + (n << 4) + fr] = acc[m][n][j];
    asm volatile("s_waitcnt lgkmcnt(0)" ::: "memory");
    const int grow = m0 + wr + (m << 4) + rrow;
    const int gcol = n0 + wc + (rq << 4);
    float val[16];
#pragma unroll
    for (int p2 = 0; p2 < 4; ++p2){
      float4 vv = *(const float4*)&slice[rrow * 68 + (rq << 4) + (p2 << 2)];
      val[p2 * 4 + 0] = vv.x; val[p2 * 4 + 1] = vv.y;
      val[p2 * 4 + 2] = vv.z; val[p2 * 4 + 3] = vv.w;
    }
    const size_t ob = (size_t)grow * N + gcol;
    if (mode == 0){
      float o0[16], o1[16];
#pragma unroll
      for (int e = 0; e < 16; ++e){
        float z = val[e] + bias[gcol + e];
        o0[e] = dgelu_f(z);
        o1[e] = gelu_f(z);
      }
      store16(outA + ob, o0);
      store16(outB + ob, o1);
    } else if (mode == 1){
      float pe = 0.f;
      float o0[16];
#pragma unroll
      for (int e = 0; e < 16; ++e){
        float z = val[e] + bias[gcol + e];
        float w3 = W3[gcol + e];
        o0[e] = w3 * dgelu_f(z);
        if (do_e) pe += gelu_f(z) * w3;
      }
      if (outB) store16(outB + ob, o0);
      if (do_e){
        pe += __shfl_xor(pe, 1);
        pe += __shfl_xor(pe, 2);
        if (rq == 0) atomicAdd(&e_lds[wr + (m << 4) + rrow], pe);
      }
    } else {
      float o0[16];
      short8v g0 = *(const short8v*)&dgz[ob];
      short8v g1 = *(const short8v*)&dgz[ob + 8];
#pragma unroll
      for (int e = 0; e < 8; ++e){
        o0[e]     = val[e]     * bf2f((ushort_t)g0[e]);
        o0[8 + e] = val[8 + e] * bf2f((ushort_t)g1[e]);
      }
      store16(outA + ob, o0);
    }
  }
  if (do_e){
    __syncthreads();
    if (t < 256) e_part[(size_t)bx * Mrows + m0 + t] = e_lds[t];
  }
}

// ============ dy GEMM: 128x128 tile, split-K x4 (grid 2 x Mc/128 x 4 = 1024 blocks) ============
#define DY_STAGE(Asl_, Bsl_, k0_) do { \
  _Pragma("unroll") \
  for (int i_ = 0; i_ < 4; ++i_){ \
    int c_ = i_ * 4 + w; \
    int r_ = c_ * 8 + rsub; \
    load_lds16((const char*)A + ((size_t)(m0 + r_) * K + (k0_)) * 2 + cb, (char*)(Asl_) + c_ * 1024 + lane * 16); \
    load_lds16((const char*)BT + ((size_t)(n0 + r_) * K + (k0_)) * 2 + cb, (char*)(Bsl_) + c_ * 1024 + lane * 16); \
  } } while (0)

#define DY_MFMA(Asl_, Bsl_) do { \
  _Pragma("unroll") \
  for (int kk = 0; kk < 2; ++kk){ \
    int kb = kk * 32 + kg * 8; \
    short8v a[4], b[4]; \
    _Pragma("unroll") \
    for (int m = 0; m < 4; ++m) a[m] = *(const short8v*)&(Asl_)[(wr + m * 16 + fr) * 64 + kb]; \
    _Pragma("unroll") \
    for (int n = 0; n < 4; ++n) b[n] = *(const short8v*)&(Bsl_)[(wc + n * 16 + fr) * 64 + kb]; \
    _Pragma("unroll") \
    for (int m = 0; m < 4; ++m) \
      _Pragma("unroll") \
      for (int n = 0; n < 4; ++n) \
        acc[m][n] = __builtin_amdgcn_mfma_f32_16x16x32_bf16(a[m], b[n], acc[m][n], 0, 0, 0); \
  } } while (0)

__global__ __launch_bounds__(256) void gemm_dy4(
    const ushort_t* __restrict__ A, const ushort_t* __restrict__ BT,
    float* __restrict__ part, int Mc){
  __shared__ __align__(16) ushort_t Asl[2][128 * 64];
  __shared__ __align__(16) ushort_t Bsl[2][128 * 64];
  const int K = HDIM;
  const int t = threadIdx.x, lane = t & 63, w = t >> 6;
  int bx = blockIdx.x, by = blockIdx.y;
  xcd_swizzle(gridDim.x, gridDim.y, bx, by);
  const int m0 = by << 7, n0 = bx << 7;
  const int ks = blockIdx.z;
  const int kbeg = ks << 9, kend = kbeg + 512;
  const int fr = lane & 15, kg = lane >> 4;
  const int rsub = lane >> 3;
  const int cb = (lane & 7) * 16;
  const int wr = (w >> 1) * 64, wc = (w & 1) * 64;

  float4v acc[4][4];
#pragma unroll
  for (int m = 0; m < 4; ++m)
#pragma unroll
    for (int n = 0; n < 4; ++n) acc[m][n] = (float4v)0.f;

  DY_STAGE(Asl[0], Bsl[0], kbeg);
  __syncthreads();
  int cur = 0;
  for (int k0 = kbeg; k0 < kend; k0 += 64){
    if (k0 + 64 < kend) DY_STAGE(Asl[cur ^ 1], Bsl[cur ^ 1], k0 + 64);
    DY_MFMA(Asl[cur], Bsl[cur]);
    __syncthreads();
    cur ^= 1;
  }

  float* pp = part + (size_t)ks * Mc * YDIM;
#pragma unroll
  for (int m = 0; m < 4; ++m){
#pragma unroll
    for (int j = 0; j < 4; ++j){
      int row = m0 + wr + m * 16 + kg * 4 + j;
#pragma unroll
      for (int n = 0; n < 4; ++n){
        int col = n0 + wc + n * 16 + fr;
        if (col < YDIM) pp[(size_t)row * YDIM + col] = acc[m][n][j];
      }
    }
  }
}

// ---------------- host ----------------
static inline char* carve(char*& p, size_t bytes){
  char* r = p; p += (bytes + 255) & ~(size_t)255; return r;
}

extern "C" void kernel_launch(void* const* d_in, const int* in_sizes, int n_in,
                              void* d_out, int out_size, void* d_ws, size_t ws_size,
                              hipStream_t stream){
  (void)in_sizes; (void)n_in; (void)out_size;
  const float* y_true  = (const float*)d_in[0];
  const float* cond    = (const float*)d_in[1];
  const int*   k_idx   = (const int*)d_in[2];
  const float* eps_pos = (const float*)d_in[3];
  const float* eps_neg = (const float*)d_in[4];
  const float* sel     = (const float*)d_in[5];
  const float* rv      = (const float*)d_in[6];
  const float* W1      = (const float*)d_in[7];
  const float* b1      = (const float*)d_in[8];
  const float* W2      = (const float*)d_in[9];
  const float* b2      = (const float*)d_in[10];
  const float* W3      = (const float*)d_in[11];
  const float* b3      = (const float*)d_in[12];
  const float* k_emb   = (const float*)d_in[13];

  char* p = (char*)d_ws;
  double* accs   = (double*)carve(p, 3 * sizeof(double));
  float* sigma_b = (float*)carve(p, (size_t)B_TOT * 4);
  float* e_pos   = (float*)carve(p, (size_t)B_TOT * 4);
  float* e_neg   = (float*)carve(p, (size_t)B_TOT * 4);
  ushort_t* W1bf = (ushort_t*)carve(p, (size_t)256 * HDIM * 2);   // rows 0..255 of W1 (dy B^T)
  ushort_t* W1T  = (ushort_t*)carve(p, (size_t)HDIM * FEATP * 2);
  ushort_t* W2bf = (ushort_t*)carve(p, (size_t)HDIM * HDIM * 2);
  ushort_t* W2T  = (ushort_t*)carve(p, (size_t)HDIM * HDIM * 2);
  size_t fixed = (size_t)(p - (char*)d_ws);

  // per sample: feat 896 + 3 H-planes (dgz1,h1,dz2) 12288 + e_part 32 + yhat/yneg 2016
  // dy partials (4 x 252 f32 = 4032 B) alias dgz1 (dead after the dz1-GEMM read it).
  const size_t per_sample = FEATP * 2 + 3 * HDIM * 2 + NPART * 4 + 2 * YDIM * 4;
  int Mc = B_TOT;
  while (Mc > 256 && fixed + (size_t)Mc * per_sample + 65536 > ws_size) Mc >>= 1;

  ushort_t* feat = (ushort_t*)carve(p, (size_t)Mc * FEATP * 2);
  ushort_t* dgz1 = (ushort_t*)carve(p, (size_t)Mc * HDIM * 2);
  ushort_t* h1   = (ushort_t*)carve(p, (size_t)Mc * HDIM * 2);
  ushort_t* dz2  = (ushort_t*)carve(p, (size_t)Mc * HDIM * 2);
  float* e_part  = (float*)carve(p, (size_t)Mc * NPART * 4);
  float* yhat    = (float*)carve(p, (size_t)Mc * YDIM * 4);
  float* yneg    = (float*)carve(p, (size_t)Mc * YDIM * 4);
  ushort_t* dz1  = h1;          // alias: h1 dead once the z2-GEMM consumed it
  float* part    = (float*)dgz1; // alias: dgz1 dead once the dz1-GEMM consumed it

  dim3 blk(256);
  k_zero_acc<<<1, 1, 0, stream>>>(accs);
  k_sigma<<<(B_TOT + 255) / 256, blk, 0, stream>>>(k_idx, sigma_b);
  k_cast<<<(256 * HDIM + 255) / 256, blk, 0, stream>>>(W1, W1bf, 256 * HDIM);
  k_w1t<<<(HDIM * FEATP + 255) / 256, blk, 0, stream>>>(W1, W1T);
  k_w2x<<<dim3(HDIM / 32, HDIM / 32), blk, 0, stream>>>(W2, W2bf, W2T);

  auto G = [&](const ushort_t* Ap, const ushort_t* BTp, int K, int mode,
               const float* biasp, ushort_t* oA, ushort_t* oB, float* ep){
    gemm_p<<<dim3(HDIM / 256, Mc / 256), dim3(512), 0, stream>>>(
        Ap, BTp, HDIM, K, mode, biasp, W3, dgz1, oA, oB, ep, Mc);
  };
  auto Gdy = [&](){
    gemm_dy4<<<dim3(2, Mc / 128, 4), blk, 0, stream>>>(dz1, W1bf, part, Mc);
  };

  int nCh = B_TOT / Mc;
  for (int c = 0; c < nCh; ++c){
    int b0 = c * Mc;
    k_feat_static<<<(Mc * 196 + 255) / 256, blk, 0, stream>>>(
        cond + (size_t)b0 * CELLS, k_emb, k_idx + b0, feat, Mc);

    // ---- positive branch
    k_noise<<<(Mc * CELLS + 255) / 256, blk, 0, stream>>>(
        y_true + (size_t)b0 * YDIM, eps_pos + (size_t)b0 * YDIM, sigma_b + b0, yhat, feat, Mc);
    G(feat, W1T, FEATP, 0, b1, dgz1, h1, nullptr);
    G(h1, W2T, HDIM, 1, b2, nullptr, dz2, e_part);
    k_esum<<<(Mc + 255) / 256, blk, 0, stream>>>(e_part, b3, e_pos + b0, Mc);
    G(dz2, W2bf, HDIM, 2, nullptr, dz1, nullptr, nullptr);
    Gdy();
    k_mse<<<512, blk, 0, stream>>>(part, yhat, y_true + (size_t)b0 * YDIM, sigma_b + b0, accs, Mc);

    // ---- negative branch
    k_makeneg<<<(Mc * 64 + 255) / 256, blk, 0, stream>>>(y_true, sel, rv, yneg, feat, b0, Mc);
    for (int r = 0; r < 5; ++r){
      G(feat, W1T, FEATP, 0, b1, dgz1, h1, nullptr);
      G(h1, W2T, HDIM, 1, b2, nullptr, dz2, nullptr);
      G(dz2, W2bf, HDIM, 2, nullptr, dz1, nullptr, nullptr);
      Gdy();
      k_upd<<<(Mc * YDIM + 255) / 256, blk, 0, stream>>>(part, yneg, feat, Mc);
    }
    k_noise<<<(Mc * CELLS + 255) / 256, blk, 0, stream>>>(
        yneg, eps_neg + (size_t)b0 * YDIM, sigma_b + b0, yhat, feat, Mc);
    G(feat, W1T, FEATP, 0, b1, dgz1, h1, nullptr);
    G(h1, W2T, HDIM, 1, b2, nullptr, nullptr, e_part);
    k_esum<<<(Mc + 255) / 256, blk, 0, stream>>>(e_part, b3, e_neg + b0, Mc);
  }

  k_contrast<<<64, blk, 0, stream>>>(e_pos, e_neg, accs);
  k_finalize<<<1, 1, 0, stream>>>(accs, (float*)d_out);
}

// Round 15
// 2827.146 us; speedup vs baseline: 1.0473x; 1.0222x over previous
//
#include <hip/hip_runtime.h>
#include <math.h>

#define B_TOT 16384
#define CELLS 36
#define YDIM 252       // 7*6*6
#define FEATP 448      // 416 padded to 448
#define FEAT_REAL 416
#define HDIM 2048
#define EMB_DIM 128
#define KSTEPS 50
#define NPART 8        // e_part slabs = HDIM/256

typedef unsigned short ushort_t;
typedef __attribute__((ext_vector_type(8))) short short8v;
typedef __attribute__((ext_vector_type(4))) float float4v;

__device__ __forceinline__ float clip01(float x){ return fminf(fmaxf(x, 0.f), 1.f); }
__device__ __forceinline__ float tanh_fast(float u){
  float e = __expf(2.f * u);
  return 1.f - 2.f / (e + 1.f);
}
__device__ __forceinline__ float gelu_f(float x){
  float u = 0.7978845608028654f * (x + 0.044715f * x * x * x);
  return 0.5f * x * (1.f + tanh_fast(u));
}
__device__ __forceinline__ float dgelu_f(float x){
  float x2 = x * x;
  float u = 0.7978845608028654f * (x + 0.044715f * x2 * x);
  float t = tanh_fast(u);
  return 0.5f * (1.f + t) + 0.5f * x * (1.f - t * t) * 0.7978845608028654f * (1.f + 0.134145f * x2);
}
__device__ __forceinline__ float clipmask(float y){ return (y == 0.f || y == 1.f) ? 0.5f : 1.f; }
__device__ __forceinline__ ushort_t f2bf(float x){
  union { float f; unsigned u; } v; v.f = x;
  unsigned r = v.u + 0x7fffu + ((v.u >> 16) & 1u);
  return (ushort_t)(r >> 16);
}
__device__ __forceinline__ float bf2f(ushort_t h){
  union { unsigned u; float f; } v; v.u = ((unsigned)h) << 16; return v.f;
}
__device__ __forceinline__ void load_lds16(const void* g, void* l){
  __builtin_amdgcn_global_load_lds((const __attribute__((address_space(1))) unsigned int*)g,
                                   (__attribute__((address_space(3))) unsigned int*)l, 16, 0, 0);
}
__device__ __forceinline__ void store16(ushort_t* dst, const float* x){
  short8v r0, r1;
#pragma unroll
  for (int i = 0; i < 8; ++i){ r0[i] = (short)f2bf(x[i]); r1[i] = (short)f2bf(x[8 + i]); }
  *(short8v*)dst = r0;
  *(short8v*)&dst[8] = r1;
}
// m204 bijective XCD swizzle
__device__ __forceinline__ void xcd_swizzle(int GX, int GY, int& bx, int& by){
  int nwg = GX * GY;
  int orig = by * GX + bx;
  int q = nwg >> 3, r = nwg & 7;
  int xcd = orig & 7, loc = orig >> 3;
  int lin = (xcd < r ? xcd * (q + 1) : r * (q + 1) + (xcd - r) * q) + loc;
  bx = lin % GX; by = lin / GX;
}

// ---------------- small kernels ----------------
__global__ void k_zero_acc(double* acc){ acc[0] = 0.0; acc[1] = 0.0; acc[2] = 0.0; }

__global__ void k_sigma(const int* __restrict__ k_idx, float* __restrict__ sigma_b){
  int b = blockIdx.x * blockDim.x + threadIdx.x;
  if (b >= B_TOT) return;
  int i = (KSTEPS - 1) - k_idx[b];
  float t = (float)i / (float)(KSTEPS - 1);
  float ang = (1.f - t) * 1.57079632679489662f;
  float c = cosf(ang);
  sigma_b[b] = 0.01f + 0.94f * c * c;
}

__global__ void k_cast(const float* __restrict__ in, ushort_t* __restrict__ out, int n){
  int gid = blockIdx.x * blockDim.x + threadIdx.x;
  if (gid < n) out[gid] = f2bf(in[gid]);
}
// W1T[h][f] (f padded to 448)
__global__ void k_w1t(const float* __restrict__ W1, ushort_t* __restrict__ W1T){
  int gid = blockIdx.x * blockDim.x + threadIdx.x;
  if (gid >= HDIM * FEATP) return;
  int h = gid / FEATP, f = gid - h * FEATP;
  W1T[gid] = (f < FEAT_REAL) ? f2bf(W1[(size_t)f * HDIM + h]) : (ushort_t)0;
}
// merged: W2bf = cast(W2) (row-major), W2T[n][k] = W2[k][n] — one read of W2
__global__ __launch_bounds__(256) void k_w2x(const float* __restrict__ W2,
                                             ushort_t* __restrict__ W2bf,
                                             ushort_t* __restrict__ W2T){
  __shared__ float tile[32][33];
  int x0 = blockIdx.x << 5, y0 = blockIdx.y << 5;
  int tx = threadIdx.x & 31, ty = threadIdx.x >> 5;
#pragma unroll
  for (int i = 0; i < 4; ++i){
    float v = W2[(size_t)(y0 + ty + i * 8) * HDIM + (x0 + tx)];
    tile[ty + i * 8][tx] = v;
    W2bf[(size_t)(y0 + ty + i * 8) * HDIM + (x0 + tx)] = f2bf(v);
  }
  __syncthreads();
#pragma unroll
  for (int i = 0; i < 4; ++i)
    W2T[(size_t)(x0 + ty + i * 8) * HDIM + (y0 + tx)] = f2bf(tile[tx][ty + i * 8]);
}

// static cols of feat: 252..447 (cond, emb, zero pad)
__global__ void k_feat_static(const float* __restrict__ cond, const float* __restrict__ k_emb,
                              const int* __restrict__ k_idx, ushort_t* __restrict__ feat, int Mc){
  int gid = blockIdx.x * blockDim.x + threadIdx.x;
  if (gid >= Mc * 196) return;
  int i = gid / 196, c = gid - i * 196;
  float v;
  if (c < CELLS)            v = cond[(size_t)i * CELLS + c];
  else if (c < CELLS + EMB_DIM) v = k_emb[(size_t)k_idx[i] * EMB_DIM + (c - CELLS)];
  else                      v = 0.f;
  feat[(size_t)i * FEATP + YDIM + c] = f2bf(v);
}

// noise + direct feat write
__global__ void k_noise(const float* __restrict__ y, const float* __restrict__ eps,
                        const float* __restrict__ sigma_b, float* __restrict__ out,
                        ushort_t* __restrict__ feat, int Mc){
  int gid = blockIdx.x * blockDim.x + threadIdx.x;
  if (gid >= Mc * CELLS) return;
  int i = gid / CELLS, cell = gid - i * CELLS;
  float sigma = sigma_b[i];
  float sq = sqrtf(fmaxf(1.f - sigma * sigma, 1e-8f));
  const float* yp = y + (size_t)i * YDIM + cell;
  const float* ep = eps + (size_t)i * YDIM + cell;
  float yh[7];
#pragma unroll
  for (int ch = 0; ch < 7; ++ch){
    float e = ep[ch * CELLS] * 0.1f;
    yh[ch] = clip01(sq * yp[ch * CELLS] + sigma * e);
  }
  bool filled = yh[0] > 0.5f;
  float s = 0.f;
#pragma unroll
  for (int ch = 1; ch < 7; ++ch) s += yh[ch];
  float* op = out + (size_t)i * YDIM + cell;
  ushort_t* fp = feat + (size_t)i * FEATP + cell;
  op[0] = yh[0];
  fp[0] = f2bf(yh[0]);
#pragma unroll
  for (int ch = 1; ch < 7; ++ch){
    float v = yh[ch];
    if (filled) v = v / (s + 1e-8f);
    v = clip01(v);
    op[ch * CELLS] = v;
    fp[ch * CELLS] = f2bf(v);
  }
}

// y_neg init + feat write
__global__ void k_makeneg(const float* __restrict__ y_true, const float* __restrict__ sel,
                          const float* __restrict__ rv, float* __restrict__ y_neg,
                          ushort_t* __restrict__ feat, int b0, int Mc){
  int w = (blockIdx.x * blockDim.x + threadIdx.x) >> 6;
  int lane = threadIdx.x & 63;
  if (w >= Mc) return;
  int b = b0 + w;
  int c = lane;
  bool active = c < CELLS;
  float yt0 = active ? y_true[(size_t)b * YDIM + c] : 0.f;
  bool filled = active && (yt0 > 0.5f);
  unsigned long long bal = __ballot(filled);
  int n_filled = __popcll(bal);
  int num_c = (int)floorf((float)n_filled * 0.3f);
  int idx = num_c - 1; if (idx < 0) idx = 0;
  float score = filled ? sel[(size_t)b * CELLS + c] : 2.0f;
  int cnt_lt = 0, cnt_le = 0;
  for (int l = 0; l < CELLS; ++l){
    float sv = __shfl(score, l);
    cnt_lt += (sv < score);
    cnt_le += (sv <= score);
  }
  float cand = (active && cnt_lt <= idx && idx < cnt_le) ? score : 3.4e38f;
  for (int off = 32; off; off >>= 1) cand = fminf(cand, __shfl_xor(cand, off));
  float thr = (num_c > 0) ? cand : -1.0f;
  bool corrupt = filled && (score <= thr);
  if (active){
    float rvv[6]; float rsum = 0.f;
#pragma unroll
    for (int ch = 0; ch < 6; ++ch){ rvv[ch] = rv[(size_t)b * (6 * CELLS) + ch * CELLS + c]; rsum += rvv[ch]; }
    float v0 = corrupt ? 0.f : yt0;
    y_neg[(size_t)w * YDIM + c] = v0;
    feat[(size_t)w * FEATP + c] = f2bf(clip01(v0));
#pragma unroll
    for (int ch = 0; ch < 6; ++ch){
      float val = corrupt ? rvv[ch] / rsum : y_true[(size_t)b * YDIM + (ch + 1) * CELLS + c];
      y_neg[(size_t)w * YDIM + (ch + 1) * CELLS + c] = val;
      feat[(size_t)w * FEATP + (ch + 1) * CELLS + c] = f2bf(clip01(val));
    }
  }
}

// e[i] = b3 + sum_x e_part[x][i]
__global__ void k_esum(const float* __restrict__ e_part, const float* __restrict__ b3,
                       float* __restrict__ e_out, int Mc){
  int i = blockIdx.x * blockDim.x + threadIdx.x;
  if (i >= Mc) return;
  float s = b3[0];
#pragma unroll
  for (int x = 0; x < NPART; ++x) s += e_part[(size_t)x * Mc + i];
  e_out[i] = s;
}

// refine update from 4 split-K bf16 partials; also refresh feat
__global__ void k_upd(const ushort_t* __restrict__ part, float* __restrict__ yneg,
                      ushort_t* __restrict__ feat, int Mc){
  int gid = blockIdx.x * blockDim.x + threadIdx.x;
  int total = Mc * YDIM;
  if (gid >= total) return;
  int i = gid / YDIM, c = gid - i * YDIM;
  float g = ((bf2f(part[gid]) + bf2f(part[(size_t)total + gid])) +
             (bf2f(part[2 * (size_t)total + gid]) + bf2f(part[3 * (size_t)total + gid])));
  float y = yneg[gid];
  y = clip01(y + 0.15f * g * clipmask(y));
  yneg[gid] = y;
  feat[(size_t)i * FEATP + c] = f2bf(y);
}

// mse: grid-stride, block-reduce, 1 atomic per block (4 bf16 partials)
__global__ __launch_bounds__(256) void k_mse(const ushort_t* __restrict__ part, const float* __restrict__ yhat,
                      const float* __restrict__ y_true, const float* __restrict__ sigma_b,
                      double* __restrict__ acc, int Mc){
  int total = Mc * YDIM;
  double v = 0.0;
  for (int gid = blockIdx.x * blockDim.x + threadIdx.x; gid < total; gid += gridDim.x * blockDim.x){
    int i = gid / YDIM;
    float y = yhat[gid];
    float dy = ((bf2f(part[gid]) + bf2f(part[(size_t)total + gid])) +
                (bf2f(part[2 * (size_t)total + gid]) + bf2f(part[3 * (size_t)total + gid])));
    float score = dy * clipmask(y);
    float sigma = sigma_b[i];
    float tgt = (y - y_true[gid]) / (sigma + 1e-8f);
    float d = score - tgt;
    v += (double)d * (double)d;
  }
  for (int off = 32; off; off >>= 1) v += __shfl_down(v, off);
  __shared__ double wsum[4];
  int lane = threadIdx.x & 63, wid = threadIdx.x >> 6;
  if (lane == 0) wsum[wid] = v;
  __syncthreads();
  if (threadIdx.x == 0) atomicAdd(&acc[0], (wsum[0] + wsum[1]) + (wsum[2] + wsum[3]));
}

__global__ __launch_bounds__(256) void k_contrast(const float* __restrict__ e_pos, const float* __restrict__ e_neg,
                           double* __restrict__ acc){
  double con = 0.0, reg = 0.0;
  for (int b = blockIdx.x * blockDim.x + threadIdx.x; b < B_TOT; b += gridDim.x * blockDim.x){
    float ep = e_pos[b], en = e_neg[b];
    float a = -ep, bb = -en;
    float m = fmaxf(a, bb);
    float lse = m + logf(expf(a - m) + expf(bb - m));
    con += (double)(ep + lse);
    reg += (double)ep + (double)en;
  }
  for (int off = 32; off; off >>= 1){ con += __shfl_down(con, off); reg += __shfl_down(reg, off); }
  __shared__ double wc[4], wr[4];
  int lane = threadIdx.x & 63, wid = threadIdx.x >> 6;
  if (lane == 0){ wc[wid] = con; wr[wid] = reg; }
  __syncthreads();
  if (threadIdx.x == 0){
    atomicAdd(&acc[1], (wc[0] + wc[1]) + (wc[2] + wc[3]));
    atomicAdd(&acc[2], (wr[0] + wr[1]) + (wr[2] + wr[3]));
  }
}

__global__ void k_finalize(const double* __restrict__ acc, float* __restrict__ out){
  double mse = acc[0] / (double)((long long)B_TOT * YDIM);
  double con = acc[1] / (double)B_TOT;
  double reg = acc[2] / (double)B_TOT;
  out[0] = (float)(mse + con + 0.01 * reg);
}

// ============ 8-phase GEMM, barrier-minimal (2 barriers/K-step) ============
// BM=BN=256, K-step 64, 512 thr = 8 waves (2M x 4N), wave tile 128x64.
// LDS 2x(A[256][64]+B[256][64]) = 128 KiB; x2-unrolled compile-time parity.
// Rows 128B = 8 slots; slot s of row r holds k-chunk (s-r)&7; read slot (chunk+fr)&7.
// Two barriers per K-step: (a) end-of-ph2 releases cur A0/B0 for ph3's t+2 stage;
// (b) end-of-ph3 + boundary vmcnt gates step t+1's reads.
// modes: 0 z1: z=v+b1 -> outA?=dgz1=bf(dgelu z), outB=h1=bf(gelu z)
//        1 z2: z=v+b2 -> outB?=dz2=bf(W3*dgelu z); e_part?=row sums gelu(z)*W3
//        2 dz1: v *= bf2f(dgz[o]); outA
#define STG_H(srcPtr, p0, buf, k0, h) \
  _Pragma("unroll") \
  for (int ro_ = 0; ro_ < 2; ++ro_){ \
    int r_ = (ro_ << 7) + ((h) << 6) + (t >> 3); \
    int c_ = ((t & 7) - r_) & 7; \
    load_lds16((const char*)(srcPtr) + (((size_t)((p0) + r_)) * K + (k0) + (c_ << 3)) * 2, \
               (char*)(buf) + (r_ << 7) + ((t & 7) << 4)); \
  }

#define K_STEP(SV, CA_, CB_, NA_, NB_) do { \
  const int s_ = (SV); \
  const int kn1_ = (s_ + 1) << 6, kn2_ = (s_ + 2) << 6; \
  short8v afa[4], afb[4], afc[4], afd[4], bf0[4], bf1[4]; \
  /* ph0: (mh0,kk0); stage B1(s+1) */ \
  _Pragma("unroll") \
  for (int n = 0; n < 4; ++n) bf0[n] = *(const short8v*)((const char*)(CB_) + brow + (n << 11) + aslot0); \
  _Pragma("unroll") \
  for (int m = 0; m < 4; ++m) afa[m] = *(const short8v*)((const char*)(CA_) + arow + (m << 11) + aslot0); \
  if (s_ + 1 < NT){ STG_H(BT, n0, (NB_), kn1_, 1); } \
  __builtin_amdgcn_s_setprio(1); \
  _Pragma("unroll") \
  for (int m = 0; m < 4; ++m) \
    _Pragma("unroll") \
    for (int n = 0; n < 4; ++n) \
      acc[m][n] = __builtin_amdgcn_mfma_f32_16x16x32_bf16(afa[m], bf0[n], acc[m][n], 0, 0, 0); \
  __builtin_amdgcn_s_setprio(0); \
  /* ph1: (mh1,kk0); stage A1(s+1) */ \
  _Pragma("unroll") \
  for (int m = 0; m < 4; ++m) afb[m] = *(const short8v*)((const char*)(CA_) + arow + ((m + 4) << 11) + aslot0); \
  if (s_ + 1 < NT){ STG_H(A, m0, (NA_), kn1_, 1); } \
  __builtin_amdgcn_s_setprio(1); \
  _Pragma("unroll") \
  for (int m = 0; m < 4; ++m) \
    _Pragma("unroll") \
    for (int n = 0; n < 4; ++n) \
      acc[m + 4][n] = __builtin_amdgcn_mfma_f32_16x16x32_bf16(afb[m], bf0[n], acc[m + 4][n], 0, 0, 0); \
  __builtin_amdgcn_s_setprio(0); \
  /* ph2: (mh0,kk1) */ \
  _Pragma("unroll") \
  for (int n = 0; n < 4; ++n) bf1[n] = *(const short8v*)((const char*)(CB_) + brow + (n << 11) + aslot1); \
  _Pragma("unroll") \
  for (int m = 0; m < 4; ++m) afc[m] = *(const short8v*)((const char*)(CA_) + arow + (m << 11) + aslot1); \
  __builtin_amdgcn_s_setprio(1); \
  _Pragma("unroll") \
  for (int m = 0; m < 4; ++m) \
    _Pragma("unroll") \
    for (int n = 0; n < 4; ++n) \
      acc[m][n] = __builtin_amdgcn_mfma_f32_16x16x32_bf16(afc[m], bf1[n], acc[m][n], 0, 0, 0); \
  __builtin_amdgcn_s_setprio(0); \
  asm volatile("s_waitcnt lgkmcnt(0)" ::: "memory"); \
  __builtin_amdgcn_s_barrier();   /* (a) release cur A0/B0 for overwrite */ \
  /* ph3: (mh1,kk1); stage A0+B0(s+2) into cur parity */ \
  _Pragma("unroll") \
  for (int m = 0; m < 4; ++m) afd[m] = *(const short8v*)((const char*)(CA_) + arow + ((m + 4) << 11) + aslot1); \
  if (s_ + 2 < NT){ STG_H(A, m0, (CA_), kn2_, 0); STG_H(BT, n0, (CB_), kn2_, 0); } \
  __builtin_amdgcn_s_setprio(1); \
  _Pragma("unroll") \
  for (int m = 0; m < 4; ++m) \
    _Pragma("unroll") \
    for (int n = 0; n < 4; ++n) \
      acc[m + 4][n] = __builtin_amdgcn_mfma_f32_16x16x32_bf16(afd[m], bf1[n], acc[m + 4][n], 0, 0, 0); \
  __builtin_amdgcn_s_setprio(0); \
  asm volatile("s_waitcnt lgkmcnt(0)" ::: "memory"); \
  if (s_ + 1 < NT){ \
    if (s_ + 2 < NT) asm volatile("s_waitcnt vmcnt(4)" ::: "memory"); \
    else             asm volatile("s_waitcnt vmcnt(0)" ::: "memory"); \
  } \
  __builtin_amdgcn_s_barrier();   /* (b) K-step boundary */ \
} while (0)

__global__ __launch_bounds__(512, 1) void gemm_p(
    const ushort_t* __restrict__ A, const ushort_t* __restrict__ BT,
    int N, int K, int mode,
    const float* __restrict__ bias, const float* __restrict__ W3,
    const ushort_t* __restrict__ dgz,
    ushort_t* __restrict__ outA, ushort_t* __restrict__ outB,
    float* __restrict__ e_part, int Mrows){
  __shared__ __align__(16) ushort_t Al[2][256 * 64];
  __shared__ __align__(16) ushort_t Bl[2][256 * 64];
  const int t = threadIdx.x, lane = t & 63, w = t >> 6;
  int bx = blockIdx.x, by = blockIdx.y;
  xcd_swizzle(gridDim.x, gridDim.y, bx, by);
  const int m0 = by << 8, n0 = bx << 8;
  const int fr = lane & 15, kg = lane >> 4;
  const int wm = w >> 2, wn = w & 3;
  const int NT = K >> 6;
  const int wr = wm << 7, wc = wn << 6;
  const int aslot0 = ((kg + fr) & 7) << 4;        // kk=0: chunk=kg
  const int aslot1 = ((4 + kg + fr) & 7) << 4;    // kk=1: chunk=4+kg
  const int arow = ((wm << 7) + fr) << 7;
  const int brow = ((wn << 6) + fr) << 7;

  float4v acc[8][4];
#pragma unroll
  for (int m = 0; m < 8; ++m)
#pragma unroll
    for (int n = 0; n < 4; ++n) acc[m][n] = (float4v)0.f;

  // prologue: K-step 0 fully, then A0(1),B0(1)
  STG_H(A, m0, &Al[0][0], 0, 0); STG_H(A, m0, &Al[0][0], 0, 1);
  STG_H(BT, n0, &Bl[0][0], 0, 0); STG_H(BT, n0, &Bl[0][0], 0, 1);
  if (NT > 1){ STG_H(A, m0, &Al[1][0], 64, 0); STG_H(BT, n0, &Bl[1][0], 64, 0); }
  if (NT > 1) asm volatile("s_waitcnt vmcnt(4)" ::: "memory");
  else        asm volatile("s_waitcnt vmcnt(0)" ::: "memory");
  __builtin_amdgcn_s_barrier();

  for (int s2 = 0; s2 + 1 < NT; s2 += 2){
    K_STEP(s2,     &Al[0][0], &Bl[0][0], &Al[1][0], &Bl[1][0]);
    K_STEP(s2 + 1, &Al[1][0], &Bl[1][0], &Al[0][0], &Bl[0][0]);
  }
  if (NT & 1) K_STEP(NT - 1, &Al[0][0], &Bl[0][0], &Al[1][0], &Bl[1][0]);

  // ---- epilogue: per-wave f32 LDS slice -> coalesced 16B bf16 stores ----
  float* slice = (float*)&Al[0][0] + w * (16 * 68);
  float* e_lds = (float*)&Bl[0][0];
  const bool do_e = (mode == 1) && (e_part != nullptr);
  if (do_e){
    if (t < 256) e_lds[t] = 0.f;
    __syncthreads();
  }
  const int rrow = lane >> 2;      // 0..15
  const int rq = lane & 3;         // 16-col group
#pragma unroll
  for (int m = 0; m < 8; ++m){
    if (m) asm volatile("s_waitcnt lgkmcnt(0)" ::: "memory");  // prior reads done before overwrite
#pragma unroll
    for (int j = 0; j < 4; ++j)
#pragma unroll
      for (int n = 0; n < 4; ++n)
        slice[((kg << 2) + j) * 68 + (n << 4) + fr] = acc[m][n][j];
    asm volatile("s_waitcnt lgkmcnt(0)" ::: "memory");
    const int grow = m0 + wr + (m << 4) + rrow;
    const int gcol = n0 + wc + (rq << 4);
    float val[16];
#pragma unroll
    for (int p2 = 0; p2 < 4; ++p2){
      float4 vv = *(const float4*)&slice[rrow * 68 + (rq << 4) + (p2 << 2)];
      val[p2 * 4 + 0] = vv.x; val[p2 * 4 + 1] = vv.y;
      val[p2 * 4 + 2] = vv.z; val[p2 * 4 + 3] = vv.w;
    }
    const size_t ob = (size_t)grow * N + gcol;
    if (mode == 0){
      float o1[16];
#pragma unroll
      for (int e = 0; e < 16; ++e){
        float z = val[e] + bias[gcol + e];
        o1[e] = gelu_f(z);
        val[e] = z;
      }
      store16(outB + ob, o1);
      if (outA){
        float o0[16];
#pragma unroll
        for (int e = 0; e < 16; ++e) o0[e] = dgelu_f(val[e]);
        store16(outA + ob, o0);
      }
    } else if (mode == 1){
      float pe = 0.f;
      float o0[16];
#pragma unroll
      for (int e = 0; e < 16; ++e){
        float z = val[e] + bias[gcol + e];
        float w3 = W3[gcol + e];
        o0[e] = w3 * dgelu_f(z);
        if (do_e) pe += gelu_f(z) * w3;
      }
      if (outB) store16(outB + ob, o0);
      if (do_e){
        pe += __shfl_xor(pe, 1);
        pe += __shfl_xor(pe, 2);
        if (rq == 0) atomicAdd(&e_lds[wr + (m << 4) + rrow], pe);
      }
    } else {
      float o0[16];
      short8v g0 = *(const short8v*)&dgz[ob];
      short8v g1 = *(const short8v*)&dgz[ob + 8];
#pragma unroll
      for (int e = 0; e < 8; ++e){
        o0[e]     = val[e]     * bf2f((ushort_t)g0[e]);
        o0[8 + e] = val[8 + e] * bf2f((ushort_t)g1[e]);
      }
      store16(outA + ob, o0);
    }
  }
  if (do_e){
    __syncthreads();
    if (t < 256) e_part[(size_t)bx * Mrows + m0 + t] = e_lds[t];
  }
}

// ============ dy GEMM: 128x128 tile, split-K x4, bf16 partials ============
#define DY_STAGE(Asl_, Bsl_, k0_) do { \
  _Pragma("unroll") \
  for (int i_ = 0; i_ < 4; ++i_){ \
    int c_ = i_ * 4 + w; \
    int r_ = c_ * 8 + rsub; \
    load_lds16((const char*)A + ((size_t)(m0 + r_) * K + (k0_)) * 2 + cb, (char*)(Asl_) + c_ * 1024 + lane * 16); \
    load_lds16((const char*)BT + ((size_t)(n0 + r_) * K + (k0_)) * 2 + cb, (char*)(Bsl_) + c_ * 1024 + lane * 16); \
  } } while (0)

#define DY_MFMA(Asl_, Bsl_) do { \
  _Pragma("unroll") \
  for (int kk = 0; kk < 2; ++kk){ \
    int kb = kk * 32 + kg * 8; \
    short8v a[4], b[4]; \
    _Pragma("unroll") \
    for (int m = 0; m < 4; ++m) a[m] = *(const short8v*)&(Asl_)[(wr + m * 16 + fr) * 64 + kb]; \
    _Pragma("unroll") \
    for (int n = 0; n < 4; ++n) b[n] = *(const short8v*)&(Bsl_)[(wc + n * 16 + fr) * 64 + kb]; \
    _Pragma("unroll") \
    for (int m = 0; m < 4; ++m) \
      _Pragma("unroll") \
      for (int n = 0; n < 4; ++n) \
        acc[m][n] = __builtin_amdgcn_mfma_f32_16x16x32_bf16(a[m], b[n], acc[m][n], 0, 0, 0); \
  } } while (0)

__global__ __launch_bounds__(256) void gemm_dy4(
    const ushort_t* __restrict__ A, const ushort_t* __restrict__ BT,
    ushort_t* __restrict__ part, int Mc){
  __shared__ __align__(16) ushort_t Asl[2][128 * 64];
  __shared__ __align__(16) ushort_t Bsl[2][128 * 64];
  const int K = HDIM;
  const int t = threadIdx.x, lane = t & 63, w = t >> 6;
  int bx = blockIdx.x, by = blockIdx.y;
  xcd_swizzle(gridDim.x, gridDim.y, bx, by);
  const int m0 = by << 7, n0 = bx << 7;
  const int ks = blockIdx.z;
  const int kbeg = ks << 9, kend = kbeg + 512;
  const int fr = lane & 15, kg = lane >> 4;
  const int rsub = lane >> 3;
  const int cb = (lane & 7) * 16;
  const int wr = (w >> 1) * 64, wc = (w & 1) * 64;

  float4v acc[4][4];
#pragma unroll
  for (int m = 0; m < 4; ++m)
#pragma unroll
    for (int n = 0; n < 4; ++n) acc[m][n] = (float4v)0.f;

  DY_STAGE(Asl[0], Bsl[0], kbeg);
  __syncthreads();
  int cur = 0;
  for (int k0 = kbeg; k0 < kend; k0 += 64){
    if (k0 + 64 < kend) DY_STAGE(Asl[cur ^ 1], Bsl[cur ^ 1], k0 + 64);
    DY_MFMA(Asl[cur], Bsl[cur]);
    __syncthreads();
    cur ^= 1;
  }

  ushort_t* pp = part + (size_t)ks * Mc * YDIM;
#pragma unroll
  for (int m = 0; m < 4; ++m){
#pragma unroll
    for (int j = 0; j < 4; ++j){
      int row = m0 + wr + m * 16 + kg * 4 + j;
#pragma unroll
      for (int n = 0; n < 4; ++n){
        int col = n0 + wc + n * 16 + fr;
        if (col < YDIM) pp[(size_t)row * YDIM + col] = f2bf(acc[m][n][j]);
      }
    }
  }
}

// ---------------- host ----------------
static inline char* carve(char*& p, size_t bytes){
  char* r = p; p += (bytes + 255) & ~(size_t)255; return r;
}

extern "C" void kernel_launch(void* const* d_in, const int* in_sizes, int n_in,
                              void* d_out, int out_size, void* d_ws, size_t ws_size,
                              hipStream_t stream){
  (void)in_sizes; (void)n_in; (void)out_size;
  const float* y_true  = (const float*)d_in[0];
  const float* cond    = (const float*)d_in[1];
  const int*   k_idx   = (const int*)d_in[2];
  const float* eps_pos = (const float*)d_in[3];
  const float* eps_neg = (const float*)d_in[4];
  const float* sel     = (const float*)d_in[5];
  const float* rv      = (const float*)d_in[6];
  const float* W1      = (const float*)d_in[7];
  const float* b1      = (const float*)d_in[8];
  const float* W2      = (const float*)d_in[9];
  const float* b2      = (const float*)d_in[10];
  const float* W3      = (const float*)d_in[11];
  const float* b3      = (const float*)d_in[12];
  const float* k_emb   = (const float*)d_in[13];

  char* p = (char*)d_ws;
  double* accs   = (double*)carve(p, 3 * sizeof(double));
  float* sigma_b = (float*)carve(p, (size_t)B_TOT * 4);
  float* e_pos   = (float*)carve(p, (size_t)B_TOT * 4);
  float* e_neg   = (float*)carve(p, (size_t)B_TOT * 4);
  ushort_t* W1bf = (ushort_t*)carve(p, (size_t)256 * HDIM * 2);   // rows 0..255 of W1 (dy B^T)
  ushort_t* W1T  = (ushort_t*)carve(p, (size_t)HDIM * FEATP * 2);
  ushort_t* W2bf = (ushort_t*)carve(p, (size_t)HDIM * HDIM * 2);
  ushort_t* W2T  = (ushort_t*)carve(p, (size_t)HDIM * HDIM * 2);
  size_t fixed = (size_t)(p - (char*)d_ws);

  // per sample: feat 896 + 3 H-planes (dgz1,h1,dz2) 12288 + e_part 32 + yhat/yneg 2016
  // dy partials (4 x 252 bf16 = 2016 B) alias dgz1 (dead after the dz1-GEMM read it).
  const size_t per_sample = FEATP * 2 + 3 * HDIM * 2 + NPART * 4 + 2 * YDIM * 4;
  int Mc = B_TOT;
  while (Mc > 256 && fixed + (size_t)Mc * per_sample + 65536 > ws_size) Mc >>= 1;

  ushort_t* feat = (ushort_t*)carve(p, (size_t)Mc * FEATP * 2);
  ushort_t* dgz1 = (ushort_t*)carve(p, (size_t)Mc * HDIM * 2);
  ushort_t* h1   = (ushort_t*)carve(p, (size_t)Mc * HDIM * 2);
  ushort_t* dz2  = (ushort_t*)carve(p, (size_t)Mc * HDIM * 2);
  float* e_part  = (float*)carve(p, (size_t)Mc * NPART * 4);
  float* yhat    = (float*)carve(p, (size_t)Mc * YDIM * 4);
  float* yneg    = (float*)carve(p, (size_t)Mc * YDIM * 4);
  ushort_t* dz1  = h1;            // alias: h1 dead once the z2-GEMM consumed it
  ushort_t* part = dgz1;          // alias: dgz1 dead once the dz1-GEMM consumed it

  dim3 blk(256);
  k_zero_acc<<<1, 1, 0, stream>>>(accs);
  k_sigma<<<(B_TOT + 255) / 256, blk, 0, stream>>>(k_idx, sigma_b);
  k_cast<<<(256 * HDIM + 255) / 256, blk, 0, stream>>>(W1, W1bf, 256 * HDIM);
  k_w1t<<<(HDIM * FEATP + 255) / 256, blk, 0, stream>>>(W1, W1T);
  k_w2x<<<dim3(HDIM / 32, HDIM / 32), blk, 0, stream>>>(W2, W2bf, W2T);

  auto G = [&](const ushort_t* Ap, const ushort_t* BTp, int K, int mode,
               const float* biasp, ushort_t* oA, ushort_t* oB, float* ep){
    gemm_p<<<dim3(HDIM / 256, Mc / 256), dim3(512), 0, stream>>>(
        Ap, BTp, HDIM, K, mode, biasp, W3, dgz1, oA, oB, ep, Mc);
  };
  auto Gdy = [&](){
    gemm_dy4<<<dim3(2, Mc / 128, 4), blk, 0, stream>>>(dz1, W1bf, part, Mc);
  };

  int nCh = B_TOT / Mc;
  for (int c = 0; c < nCh; ++c){
    int b0 = c * Mc;
    k_feat_static<<<(Mc * 196 + 255) / 256, blk, 0, stream>>>(
        cond + (size_t)b0 * CELLS, k_emb, k_idx + b0, feat, Mc);

    // ---- positive branch
    k_noise<<<(Mc * CELLS + 255) / 256, blk, 0, stream>>>(
        y_true + (size_t)b0 * YDIM, eps_pos + (size_t)b0 * YDIM, sigma_b + b0, yhat, feat, Mc);
    G(feat, W1T, FEATP, 0, b1, dgz1, h1, nullptr);
    G(h1, W2T, HDIM, 1, b2, nullptr, dz2, e_part);
    k_esum<<<(Mc + 255) / 256, blk, 0, stream>>>(e_part, b3, e_pos + b0, Mc);
    G(dz2, W2bf, HDIM, 2, nullptr, dz1, nullptr, nullptr);
    Gdy();
    k_mse<<<512, blk, 0, stream>>>(part, yhat, y_true + (size_t)b0 * YDIM, sigma_b + b0, accs, Mc);

    // ---- negative branch
    k_makeneg<<<(Mc * 64 + 255) / 256, blk, 0, stream>>>(y_true, sel, rv, yneg, feat, b0, Mc);
    for (int r = 0; r < 5; ++r){
      G(feat, W1T, FEATP, 0, b1, dgz1, h1, nullptr);
      G(h1, W2T, HDIM, 1, b2, nullptr, dz2, nullptr);
      G(dz2, W2bf, HDIM, 2, nullptr, dz1, nullptr, nullptr);
      Gdy();
      k_upd<<<(Mc * YDIM + 255) / 256, blk, 0, stream>>>(part, yneg, feat, Mc);
    }
    k_noise<<<(Mc * CELLS + 255) / 256, blk, 0, stream>>>(
        yneg, eps_neg + (size_t)b0 * YDIM, sigma_b + b0, yhat, feat, Mc);
    G(feat, W1T, FEATP, 0, b1, nullptr, h1, nullptr);   // final fwd: dgz1 never consumed
    G(h1, W2T, HDIM, 1, b2, nullptr, nullptr, e_part);
    k_esum<<<(Mc + 255) / 256, blk, 0, stream>>>(e_part, b3, e_neg + b0, Mc);
  }

  k_contrast<<<64, blk, 0, stream>>>(e_pos, e_neg, accs);
  k_finalize<<<1, 1, 0, stream>>>(accs, (float*)d_out);
}